// Round 1
// baseline (5000.433 us; speedup 1.0000x reference)
//
#include <hip/hip_runtime.h>
#include <math.h>

#define E_DIM 384
#define N_HEAD 6
#define HEAD_SZ 64
#define SEQ 256
#define BATCH 16
#define NTOK 4096   // BATCH*SEQ
#define NLAYER 6
#define VOCAB 50257

// ---------------- embedding: x[m][e] = tok[idx[m]][e] + pos[m%SEQ][e] ----------------
__global__ void embed_kernel(const int* __restrict__ idx,
                             const float* __restrict__ tok,
                             const float* __restrict__ pos,
                             float* __restrict__ x) {
    int i = blockIdx.x * blockDim.x + threadIdx.x;
    if (i >= NTOK * E_DIM) return;
    int m = i / E_DIM, e = i - m * E_DIM;
    int t = m & (SEQ - 1);
    x[i] = tok[(size_t)idx[m] * E_DIM + e] + pos[t * E_DIM + e];
}

// ---------------- layernorm: one wave per row (E=384 = 6 per lane) ----------------
__global__ __launch_bounds__(256) void ln_kernel(const float* __restrict__ x,
                                                 const float* __restrict__ g,
                                                 const float* __restrict__ b,
                                                 float* __restrict__ h) {
    int lane = threadIdx.x & 63;
    int wave = threadIdx.x >> 6;
    int row  = blockIdx.x * 4 + wave;
    const float* xr = x + (size_t)row * E_DIM;
    float v[6];
    float s = 0.f;
#pragma unroll
    for (int c = 0; c < 6; ++c) { v[c] = xr[lane + 64 * c]; s += v[c]; }
#pragma unroll
    for (int off = 32; off > 0; off >>= 1) s += __shfl_xor(s, off);
    float mu = s * (1.0f / E_DIM);
    float s2 = 0.f;
#pragma unroll
    for (int c = 0; c < 6; ++c) { float d = v[c] - mu; s2 += d * d; }
#pragma unroll
    for (int off = 32; off > 0; off >>= 1) s2 += __shfl_xor(s2, off);
    float rstd = rsqrtf(s2 * (1.0f / E_DIM) + 1e-5f);
    float* hr = h + (size_t)row * E_DIM;
#pragma unroll
    for (int c = 0; c < 6; ++c) {
        int e = lane + 64 * c;
        hr[e] = (v[c] - mu) * rstd * g[e] + b[e];
    }
}

// ---------------- tiled f32 GEMM: C[4096,N] = A[4096,K] @ B[K,N] (+modes) ----------
// MODE 0: C = A@B          MODE 1: C += A@B + bias
// MODE 2: C += relu(A@B + bias)                MODE 3: C = A@B + bias
// BM=BN=64, BK=16, 256 threads, 4x4 per thread. M assumed multiple of 64, K of 16.
template <int MODE>
__global__ __launch_bounds__(256) void gemm64(const float* __restrict__ A,
                                              const float* __restrict__ Bm,
                                              const float* __restrict__ bias,
                                              float* C, int N, int K) {
    __shared__ float As[16][68];  // As[k][m] (transposed so frag reads are b128)
    __shared__ float Bs[16][68];  // Bs[k][n]
    int tid = threadIdx.x;
    int tx = tid & 15, ty = tid >> 4;
    int row0 = blockIdx.y * 64, col0 = blockIdx.x * 64;
    float acc[4][4];
#pragma unroll
    for (int i = 0; i < 4; ++i)
#pragma unroll
        for (int j = 0; j < 4; ++j) acc[i][j] = 0.f;

    int arow = tid >> 2, ak = (tid & 3) << 2;   // A tile: 64 rows x 16 k
    int bk = tid >> 4, bc = (tid & 15) << 2;    // B tile: 16 k x 64 cols

    for (int k0 = 0; k0 < K; k0 += 16) {
        float4 a4 = *(const float4*)(A + (size_t)(row0 + arow) * K + k0 + ak);
        As[ak + 0][arow] = a4.x;
        As[ak + 1][arow] = a4.y;
        As[ak + 2][arow] = a4.z;
        As[ak + 3][arow] = a4.w;
        const float* Bp = Bm + (size_t)(k0 + bk) * N + col0 + bc;
        int cb = col0 + bc;  // N may be odd (50257): scalar, bounds-checked
        Bs[bk][bc + 0] = (cb + 0 < N) ? Bp[0] : 0.f;
        Bs[bk][bc + 1] = (cb + 1 < N) ? Bp[1] : 0.f;
        Bs[bk][bc + 2] = (cb + 2 < N) ? Bp[2] : 0.f;
        Bs[bk][bc + 3] = (cb + 3 < N) ? Bp[3] : 0.f;
        __syncthreads();
#pragma unroll
        for (int kk = 0; kk < 16; ++kk) {
            float4 av = *(const float4*)(&As[kk][ty << 2]);
            float4 bv = *(const float4*)(&Bs[kk][tx << 2]);
            float aa[4] = {av.x, av.y, av.z, av.w};
            float bb[4] = {bv.x, bv.y, bv.z, bv.w};
#pragma unroll
            for (int i = 0; i < 4; ++i)
#pragma unroll
                for (int j = 0; j < 4; ++j) acc[i][j] = fmaf(aa[i], bb[j], acc[i][j]);
        }
        __syncthreads();
    }
#pragma unroll
    for (int i = 0; i < 4; ++i) {
        int r = row0 + (ty << 2) + i;
        float* Cr = C + (size_t)r * N;
#pragma unroll
        for (int j = 0; j < 4; ++j) {
            int c = col0 + (tx << 2) + j;
            if (c < N) {
                float val = acc[i][j];
                if (MODE == 1) val = Cr[c] + val + bias[c];
                else if (MODE == 2) { float u = val + bias[c]; val = Cr[c] + fmaxf(u, 0.f); }
                else if (MODE == 3) val += bias[c];
                Cr[c] = val;
            }
        }
    }
}

// ---------------- attention: one wave per query row ----------------
// s = (q.k^T masked to j<=t) * 1/8 ; p = softmax(s) ; o = p @ v
__global__ __launch_bounds__(256) void attn_kernel(const float* __restrict__ q,
                                                   const float* __restrict__ k,
                                                   const float* __restrict__ v,
                                                   float* __restrict__ o) {
    __shared__ float qs[4][64];
    __shared__ float ps[4][256];
    int lane = threadIdx.x & 63;
    int w = threadIdx.x >> 6;
    int bh = blockIdx.x >> 6;   // 0..95  (b*6+h)
    int rb = blockIdx.x & 63;   // 0..63
    int b = bh / N_HEAD, hh = bh - b * N_HEAD;
    int t = rb * 4 + w;
    size_t rowbase = (size_t)(b * SEQ + t) * E_DIM + hh * HEAD_SZ;
    qs[w][lane] = q[rowbase + lane];
    __syncthreads();

    float sloc[4];
    float mmax = -INFINITY;
#pragma unroll
    for (int c = 0; c < 4; ++c) {
        int j = c * 64 + lane;
        float s = -INFINITY;
        if (j <= t) {
            const float* krow = k + (size_t)(b * SEQ + j) * E_DIM + hh * HEAD_SZ;
            float a = 0.f;
#pragma unroll 16
            for (int d = 0; d < 64; ++d) a = fmaf(qs[w][d], krow[d], a);
            s = a * 0.125f;   // 1/sqrt(64)
        }
        sloc[c] = s;
        mmax = fmaxf(mmax, s);
    }
#pragma unroll
    for (int off = 32; off > 0; off >>= 1) mmax = fmaxf(mmax, __shfl_xor(mmax, off));
    float lsum = 0.f;
#pragma unroll
    for (int c = 0; c < 4; ++c) {
        float p = __expf(sloc[c] - mmax);   // exp(-inf) = 0 handles the mask
        ps[w][c * 64 + lane] = p;
        lsum += p;
    }
#pragma unroll
    for (int off = 32; off > 0; off >>= 1) lsum += __shfl_xor(lsum, off);
    __syncthreads();

    float a = 0.f;
    const float* vb = v + (size_t)(b * SEQ) * E_DIM + hh * HEAD_SZ + lane;
#pragma unroll 8
    for (int j = 0; j <= t; ++j) a += ps[w][j] * vb[(size_t)j * E_DIM];
    o[rowbase + lane] = a * (1.0f / lsum);
}

extern "C" void kernel_launch(void* const* d_in, const int* in_sizes, int n_in,
                              void* d_out, int out_size, void* d_ws, size_t ws_size,
                              hipStream_t stream) {
    const int*   idx  = (const int*)d_in[0];
    const float* tok  = (const float*)d_in[1];
    const float* pos  = (const float*)d_in[2];
    const float* Wq   = (const float*)d_in[3];
    const float* Wk   = (const float*)d_in[4];
    const float* Wv   = (const float*)d_in[5];
    const float* Wo   = (const float*)d_in[6];
    const float* bo   = (const float*)d_in[7];
    const float* ln1g = (const float*)d_in[8];
    const float* ln1b = (const float*)d_in[9];
    const float* ln2g = (const float*)d_in[10];
    const float* ln2b = (const float*)d_in[11];
    const float* Wm   = (const float*)d_in[12];
    const float* bm   = (const float*)d_in[13];
    const float* lnfg = (const float*)d_in[14];
    const float* lnfb = (const float*)d_in[15];
    const float* Wlm  = (const float*)d_in[16];
    const float* blm  = (const float*)d_in[17];
    float* out = (float*)d_out;

    const size_t BUF = (size_t)NTOK * E_DIM;  // 1.57M floats
    float* x  = (float*)d_ws;
    float* h  = x + BUF;
    float* qb = h + BUF;
    float* kb = qb + BUF;
    float* vb = kb + BUF;

    embed_kernel<<<(NTOK * E_DIM + 255) / 256, 256, 0, stream>>>(idx, tok, pos, x);

    dim3 gsmall(E_DIM / 64, NTOK / 64);  // (6, 64)
    for (int l = 0; l < NLAYER; ++l) {
        const float* wq = Wq + (size_t)l * E_DIM * E_DIM;
        const float* wk = Wk + (size_t)l * E_DIM * E_DIM;
        const float* wv = Wv + (size_t)l * E_DIM * E_DIM;
        const float* wo = Wo + (size_t)l * E_DIM * E_DIM;
        const float* wm = Wm + (size_t)l * E_DIM * E_DIM;

        ln_kernel<<<NTOK / 4, 256, 0, stream>>>(x, ln1g + l * E_DIM, ln1b + l * E_DIM, h);
        gemm64<0><<<gsmall, 256, 0, stream>>>(h, wq, nullptr, qb, E_DIM, E_DIM);
        gemm64<0><<<gsmall, 256, 0, stream>>>(h, wk, nullptr, kb, E_DIM, E_DIM);
        gemm64<0><<<gsmall, 256, 0, stream>>>(h, wv, nullptr, vb, E_DIM, E_DIM);
        attn_kernel<<<BATCH * N_HEAD * (SEQ / 4), 256, 0, stream>>>(qb, kb, vb, h);
        gemm64<1><<<gsmall, 256, 0, stream>>>(h, wo, bo + l * E_DIM, x, E_DIM, E_DIM);
        ln_kernel<<<NTOK / 4, 256, 0, stream>>>(x, ln2g + l * E_DIM, ln2b + l * E_DIM, h);
        gemm64<2><<<gsmall, 256, 0, stream>>>(h, wm, bm + l * E_DIM, x, E_DIM, E_DIM);
    }
    ln_kernel<<<NTOK / 4, 256, 0, stream>>>(x, lnfg, lnfb, h);

    dim3 glm((VOCAB + 63) / 64, NTOK / 64);  // (786, 64)
    gemm64<3><<<glm, 256, 0, stream>>>(h, Wlm, blm, out, VOCAB, E_DIM);
}

// Round 2
// 1922.040 us; speedup vs baseline: 2.6016x; 2.6016x over previous
//
#include <hip/hip_runtime.h>
#include <hip/hip_bf16.h>
#include <math.h>

#define E_DIM 384
#define N_HEAD 6
#define HEAD_SZ 64
#define SEQ 256
#define BATCH 16
#define NTOK 4096
#define NLAYER 6
#define VOCAB 50257
#define VPAD 50304          // 393*128
#define QKV_N 1152          // 3*E

typedef __attribute__((ext_vector_type(8))) short bf16x8;
typedef __attribute__((ext_vector_type(4))) float f32x4;

// ---------------- embedding ----------------
__global__ void embed_kernel(const int* __restrict__ idx,
                             const float* __restrict__ tok,
                             const float* __restrict__ pos,
                             float* __restrict__ x) {
    int i = blockIdx.x * blockDim.x + threadIdx.x;
    if (i >= NTOK * E_DIM) return;
    int m = i / E_DIM, e = i - m * E_DIM;
    int t = m & (SEQ - 1);
    x[i] = tok[(size_t)idx[m] * E_DIM + e] + pos[t * E_DIM + e];
}

// ---------------- layernorm: one wave per row, bf16 out ----------------
__global__ __launch_bounds__(256) void ln_kernel(const float* __restrict__ x,
                                                 const float* __restrict__ g,
                                                 const float* __restrict__ b,
                                                 __hip_bfloat16* __restrict__ h) {
    int lane = threadIdx.x & 63;
    int wave = threadIdx.x >> 6;
    int row  = blockIdx.x * 4 + wave;
    const float* xr = x + (size_t)row * E_DIM;
    float v[6];
    float s = 0.f;
#pragma unroll
    for (int c = 0; c < 6; ++c) { v[c] = xr[lane + 64 * c]; s += v[c]; }
#pragma unroll
    for (int off = 32; off > 0; off >>= 1) s += __shfl_xor(s, off);
    float mu = s * (1.0f / E_DIM);
    float s2 = 0.f;
#pragma unroll
    for (int c = 0; c < 6; ++c) { float d = v[c] - mu; s2 += d * d; }
#pragma unroll
    for (int off = 32; off > 0; off >>= 1) s2 += __shfl_xor(s2, off);
    float rstd = rsqrtf(s2 * (1.0f / E_DIM) + 1e-5f);
    __hip_bfloat16* hr = h + (size_t)row * E_DIM;
#pragma unroll
    for (int c = 0; c < 6; ++c) {
        int e = lane + 64 * c;
        hr[e] = __float2bfloat16((v[c] - mu) * rstd * g[e] + b[e]);
    }
}

// ---------------- weight transpose + f32->bf16 convert ----------------
// src: f32 [K][N] row-major. dst: bf16 [Npad][K] (i.e. B^T), zero-padded rows.
__device__ __forceinline__ void tconv_tile(const float* __restrict__ src,
                                           __hip_bfloat16* __restrict__ dst,
                                           int K, int N, int n0, int k0) {
    __shared__ float tbuf[64][65];
    int c = threadIdx.x & 63, r4 = threadIdx.x >> 6;
#pragma unroll
    for (int i = 0; i < 16; ++i) {
        int r = r4 * 16 + i;
        float v = 0.f;
        if (n0 + c < N) v = src[(size_t)(k0 + r) * N + n0 + c];
        tbuf[r][c] = v;
    }
    __syncthreads();
#pragma unroll
    for (int i = 0; i < 16; ++i) {
        int rn = r4 * 16 + i;
        dst[(size_t)(n0 + rn) * K + k0 + c] = __float2bfloat16(tbuf[c][rn]);
    }
}

// all per-layer weights -> WtL[l]: rows [0,1152)=Wq^T|Wk^T|Wv^T, [1152,1536)=Wo^T, [1536,1920)=Wm^T
__global__ __launch_bounds__(256) void tconv_layers(const float* __restrict__ Wq,
                                                    const float* __restrict__ Wk,
                                                    const float* __restrict__ Wv,
                                                    const float* __restrict__ Wo,
                                                    const float* __restrict__ Wm,
                                                    __hip_bfloat16* __restrict__ WtL) {
    int z = blockIdx.z;
    int l = z / 5, t = z - l * 5;
    const float* src;
    int dstoff;
    switch (t) {
        case 0: src = Wq; dstoff = 0;    break;
        case 1: src = Wk; dstoff = 384;  break;
        case 2: src = Wv; dstoff = 768;  break;
        case 3: src = Wo; dstoff = 1152; break;
        default: src = Wm; dstoff = 1536;
    }
    src += (size_t)l * E_DIM * E_DIM;
    __hip_bfloat16* dst = WtL + ((size_t)l * 1920 + dstoff) * E_DIM;
    tconv_tile(src, dst, E_DIM, E_DIM, blockIdx.x * 64, blockIdx.y * 64);
}

__global__ __launch_bounds__(256) void tconv_lm(const float* __restrict__ Wlm,
                                                __hip_bfloat16* __restrict__ dst) {
    tconv_tile(Wlm, dst, E_DIM, VOCAB, blockIdx.x * 64, blockIdx.y * 64);
}

// ---------------- bf16 MFMA GEMM: C[M][N] = A[M][K]bf16 @ Bt^T, Bt=[Npad][K]bf16 ----
// 128x128 tile, BK=64, 4 waves (2x2), 4x4 16x16x32 frags per wave.
// MODE 0: C = AB    MODE 1: C += AB + bias    MODE 2: C += relu(AB+bias)   MODE 3: C = AB + bias (N-bounds)
__device__ __forceinline__ void gload16(const void* g, void* l) {
    __builtin_amdgcn_global_load_lds((const __attribute__((address_space(1))) char*)g,
                                     (__attribute__((address_space(3))) char*)l, 16, 0, 0);
}

template <int MODE>
__global__ __launch_bounds__(256) void mgemm(const __hip_bfloat16* __restrict__ A,
                                             const __hip_bfloat16* __restrict__ Bt,
                                             const float* __restrict__ bias,
                                             float* __restrict__ C,
                                             int N, int K) {
    __shared__ __align__(1024) char lds[32768];
    char* Ar = lds;            // A tile: logical [128 rows][64 k] bf16, XOR-swizzled
    char* Br = lds + 16384;    // B tile: logical [128 cols][64 k] bf16, XOR-swizzled
    int tid = threadIdx.x;
    int lane = tid & 63, w = tid >> 6;
    int wm = w >> 1, wn = w & 1;
    int row0 = blockIdx.y * 128;
    int col0 = blockIdx.x * 128;

    f32x4 acc[4][4];
#pragma unroll
    for (int i = 0; i < 4; ++i)
#pragma unroll
        for (int j = 0; j < 4; ++j) acc[i][j] = (f32x4){0.f, 0.f, 0.f, 0.f};

    for (int k0 = 0; k0 < K; k0 += 64) {
        __syncthreads();   // previous compute done before LDS overwrite
#pragma unroll
        for (int i = 0; i < 4; ++i) {
            int p  = i * 4096 + tid * 16;          // phys byte offset in tile
            int lg = p ^ (((p >> 7) & 7) << 4);    // logical byte (involution, row-preserving)
            int r  = lg >> 7, cb = lg & 127;
            gload16((const char*)(A  + (size_t)(row0 + r) * K + k0) + cb, Ar + i * 4096 + w * 1024);
            gload16((const char*)(Bt + (size_t)(col0 + r) * K + k0) + cb, Br + i * 4096 + w * 1024);
        }
        __syncthreads();   // compiler drains vmcnt(0) before barrier
#pragma unroll
        for (int ks = 0; ks < 2; ++ks) {
            bf16x8 af[4], bfr[4];
#pragma unroll
            for (int mi = 0; mi < 4; ++mi) {
                int rl = wm * 64 + mi * 16 + (lane & 15);
                int lg = rl * 128 + (ks * 32 + (lane >> 4) * 8) * 2;
                int ph = lg ^ ((rl & 7) << 4);
                af[mi] = *(const bf16x8*)(Ar + ph);
            }
#pragma unroll
            for (int ni = 0; ni < 4; ++ni) {
                int rl = wn * 64 + ni * 16 + (lane & 15);
                int lg = rl * 128 + (ks * 32 + (lane >> 4) * 8) * 2;
                int ph = lg ^ ((rl & 7) << 4);
                bfr[ni] = *(const bf16x8*)(Br + ph);
            }
#pragma unroll
            for (int mi = 0; mi < 4; ++mi)
#pragma unroll
                for (int ni = 0; ni < 4; ++ni)
                    acc[mi][ni] = __builtin_amdgcn_mfma_f32_16x16x32_bf16(
                        af[mi], bfr[ni], acc[mi][ni], 0, 0, 0);
        }
    }

    // epilogue: C/D layout col=lane&15, row=(lane>>4)*4+reg (measured m89/m91)
#pragma unroll
    for (int mi = 0; mi < 4; ++mi) {
#pragma unroll
        for (int ni = 0; ni < 4; ++ni) {
            int gr = row0 + wm * 64 + mi * 16 + ((lane >> 4) << 2);
            int gc = col0 + wn * 64 + ni * 16 + (lane & 15);
            if (MODE != 3 || gc < N) {
                float bv = (MODE == 0) ? 0.f : bias[gc];
#pragma unroll
                for (int j = 0; j < 4; ++j) {
                    float* cp = C + (size_t)(gr + j) * N + gc;
                    float v = acc[mi][ni][j];
                    if (MODE == 0)      *cp = v;
                    else if (MODE == 1) *cp = *cp + v + bv;
                    else if (MODE == 2) *cp = *cp + fmaxf(v + bv, 0.f);
                    else                *cp = v + bv;
                }
            }
        }
    }
}

// ---------------- attention: one wave per query row; reads fused qkv f32 ----------
__global__ __launch_bounds__(256) void attn_kernel(const float* __restrict__ qkv,
                                                   __hip_bfloat16* __restrict__ o) {
    __shared__ float qs[4][64];
    __shared__ float ps[4][256];
    int lane = threadIdx.x & 63;
    int w = threadIdx.x >> 6;
    int bh = blockIdx.x >> 6;
    int rb = blockIdx.x & 63;
    int b = bh / N_HEAD, hh = bh - b * N_HEAD;
    int t = rb * 4 + w;
    qs[w][lane] = qkv[(size_t)(b * SEQ + t) * QKV_N + hh * HEAD_SZ + lane];
    __syncthreads();

    float sloc[4];
    float mmax = -INFINITY;
#pragma unroll
    for (int c = 0; c < 4; ++c) {
        int j = c * 64 + lane;
        float s = -INFINITY;
        if (j <= t) {
            const float* krow = qkv + (size_t)(b * SEQ + j) * QKV_N + E_DIM + hh * HEAD_SZ;
            float a = 0.f;
#pragma unroll 16
            for (int d = 0; d < 64; ++d) a = fmaf(qs[w][d], krow[d], a);
            s = a * 0.125f;
        }
        sloc[c] = s;
        mmax = fmaxf(mmax, s);
    }
#pragma unroll
    for (int off = 32; off > 0; off >>= 1) mmax = fmaxf(mmax, __shfl_xor(mmax, off));
    float lsum = 0.f;
#pragma unroll
    for (int c = 0; c < 4; ++c) {
        float p = __expf(sloc[c] - mmax);
        ps[w][c * 64 + lane] = p;
        lsum += p;
    }
#pragma unroll
    for (int off = 32; off > 0; off >>= 1) lsum += __shfl_xor(lsum, off);
    __syncthreads();

    float a = 0.f;
    const float* vb = qkv + (size_t)(b * SEQ) * QKV_N + 2 * E_DIM + hh * HEAD_SZ + lane;
#pragma unroll 8
    for (int j = 0; j <= t; ++j) a += ps[w][j] * vb[(size_t)j * QKV_N];
    o[(size_t)(b * SEQ + t) * E_DIM + hh * HEAD_SZ + lane] = __float2bfloat16(a * (1.0f / lsum));
}

extern "C" void kernel_launch(void* const* d_in, const int* in_sizes, int n_in,
                              void* d_out, int out_size, void* d_ws, size_t ws_size,
                              hipStream_t stream) {
    const int*   idx  = (const int*)d_in[0];
    const float* tok  = (const float*)d_in[1];
    const float* pos  = (const float*)d_in[2];
    const float* Wq   = (const float*)d_in[3];
    const float* Wk   = (const float*)d_in[4];
    const float* Wv   = (const float*)d_in[5];
    const float* Wo   = (const float*)d_in[6];
    const float* bo   = (const float*)d_in[7];
    const float* ln1g = (const float*)d_in[8];
    const float* ln1b = (const float*)d_in[9];
    const float* ln2g = (const float*)d_in[10];
    const float* ln2b = (const float*)d_in[11];
    const float* Wm   = (const float*)d_in[12];
    const float* bm   = (const float*)d_in[13];
    const float* lnfg = (const float*)d_in[14];
    const float* lnfb = (const float*)d_in[15];
    const float* Wlm  = (const float*)d_in[16];
    const float* blm  = (const float*)d_in[17];
    float* out = (float*)d_out;

    // workspace layout (~76 MB)
    float*           x    = (float*)d_ws;                        // 4096*384 f32
    __hip_bfloat16*  hb   = (__hip_bfloat16*)(x + (size_t)NTOK * E_DIM);
    float*           qkv  = (float*)(hb + (size_t)NTOK * E_DIM); // 4096*1152 f32
    __hip_bfloat16*  WtL  = (__hip_bfloat16*)(qkv + (size_t)NTOK * QKV_N);
    __hip_bfloat16*  WtLM = WtL + (size_t)NLAYER * 1920 * E_DIM; // [50304][384] bf16

    embed_kernel<<<(NTOK * E_DIM + 255) / 256, 256, 0, stream>>>(idx, tok, pos, x);
    tconv_layers<<<dim3(6, 6, NLAYER * 5), 256, 0, stream>>>(Wq, Wk, Wv, Wo, Wm, WtL);
    tconv_lm<<<dim3(VPAD / 64, E_DIM / 64), 256, 0, stream>>>(Wlm, WtLM);

    for (int l = 0; l < NLAYER; ++l) {
        const __hip_bfloat16* wl = WtL + (size_t)l * 1920 * E_DIM;
        ln_kernel<<<NTOK / 4, 256, 0, stream>>>(x, ln1g + l * E_DIM, ln1b + l * E_DIM, hb);
        mgemm<0><<<dim3(QKV_N / 128, NTOK / 128), 256, 0, stream>>>(hb, wl, nullptr, qkv, QKV_N, E_DIM);
        attn_kernel<<<BATCH * N_HEAD * (SEQ / 4), 256, 0, stream>>>(qkv, hb);
        mgemm<1><<<dim3(E_DIM / 128, NTOK / 128), 256, 0, stream>>>(hb, wl + (size_t)1152 * E_DIM,
                                                                    bo + l * E_DIM, x, E_DIM, E_DIM);
        ln_kernel<<<NTOK / 4, 256, 0, stream>>>(x, ln2g + l * E_DIM, ln2b + l * E_DIM, hb);
        mgemm<2><<<dim3(E_DIM / 128, NTOK / 128), 256, 0, stream>>>(hb, wl + (size_t)1536 * E_DIM,
                                                                    bm + l * E_DIM, x, E_DIM, E_DIM);
    }
    ln_kernel<<<NTOK / 4, 256, 0, stream>>>(x, lnfg, lnfb, hb);
    mgemm<3><<<dim3(VPAD / 128, NTOK / 128), 256, 0, stream>>>(hb, WtLM, blm, out, VOCAB, E_DIM);
}

// Round 3
// 993.242 us; speedup vs baseline: 5.0345x; 1.9351x over previous
//
#include <hip/hip_runtime.h>
#include <hip/hip_bf16.h>
#include <math.h>

#define E_DIM 384
#define N_HEAD 6
#define HEAD_SZ 64
#define SEQ 256
#define BATCH 16
#define NTOK 4096
#define NLAYER 6
#define VOCAB 50257
#define VPAD 50304          // 393*128
#define QKV_N 1152          // 3*E
#define NBH 96              // BATCH*N_HEAD

typedef __attribute__((ext_vector_type(8))) short bf16x8;
typedef __attribute__((ext_vector_type(4))) float f32x4;
typedef __attribute__((ext_vector_type(8))) unsigned short ushort8v;

__device__ __forceinline__ unsigned short f2bu(float x) {
    __hip_bfloat16 h = __float2bfloat16(x);
    return *reinterpret_cast<unsigned short*>(&h);
}

// ---------------- embedding ----------------
__global__ void embed_kernel(const int* __restrict__ idx,
                             const float* __restrict__ tok,
                             const float* __restrict__ pos,
                             float* __restrict__ x) {
    int i = blockIdx.x * blockDim.x + threadIdx.x;
    if (i >= NTOK * E_DIM) return;
    int m = i / E_DIM, e = i - m * E_DIM;
    int t = m & (SEQ - 1);
    x[i] = tok[(size_t)idx[m] * E_DIM + e] + pos[t * E_DIM + e];
}

// ---------------- layernorm: one wave per row, bf16 out ----------------
__global__ __launch_bounds__(256) void ln_kernel(const float* __restrict__ x,
                                                 const float* __restrict__ g,
                                                 const float* __restrict__ b,
                                                 __hip_bfloat16* __restrict__ h) {
    int lane = threadIdx.x & 63;
    int wave = threadIdx.x >> 6;
    int row  = blockIdx.x * 4 + wave;
    const float* xr = x + (size_t)row * E_DIM;
    float v[6];
    float s = 0.f;
#pragma unroll
    for (int c = 0; c < 6; ++c) { v[c] = xr[lane + 64 * c]; s += v[c]; }
#pragma unroll
    for (int off = 32; off > 0; off >>= 1) s += __shfl_xor(s, off);
    float mu = s * (1.0f / E_DIM);
    float s2 = 0.f;
#pragma unroll
    for (int c = 0; c < 6; ++c) { float d = v[c] - mu; s2 += d * d; }
#pragma unroll
    for (int off = 32; off > 0; off >>= 1) s2 += __shfl_xor(s2, off);
    float rstd = rsqrtf(s2 * (1.0f / E_DIM) + 1e-5f);
    __hip_bfloat16* hr = h + (size_t)row * E_DIM;
#pragma unroll
    for (int c = 0; c < 6; ++c) {
        int e = lane + 64 * c;
        hr[e] = __float2bfloat16((v[c] - mu) * rstd * g[e] + b[e]);
    }
}

// ---------------- weight transpose + f32->bf16 convert ----------------
__device__ __forceinline__ void tconv_tile(const float* __restrict__ src,
                                           __hip_bfloat16* __restrict__ dst,
                                           int K, int N, int n0, int k0) {
    __shared__ float tbuf[64][65];
    int c = threadIdx.x & 63, r4 = threadIdx.x >> 6;
#pragma unroll
    for (int i = 0; i < 16; ++i) {
        int r = r4 * 16 + i;
        float v = 0.f;
        if (n0 + c < N) v = src[(size_t)(k0 + r) * N + n0 + c];
        tbuf[r][c] = v;
    }
    __syncthreads();
#pragma unroll
    for (int i = 0; i < 16; ++i) {
        int rn = r4 * 16 + i;
        dst[(size_t)(n0 + rn) * K + k0 + c] = __float2bfloat16(tbuf[c][rn]);
    }
}

__global__ __launch_bounds__(256) void tconv_layers(const float* __restrict__ Wq,
                                                    const float* __restrict__ Wk,
                                                    const float* __restrict__ Wv,
                                                    const float* __restrict__ Wo,
                                                    const float* __restrict__ Wm,
                                                    __hip_bfloat16* __restrict__ WtL) {
    int z = blockIdx.z;
    int l = z / 5, t = z - l * 5;
    const float* src;
    int dstoff;
    switch (t) {
        case 0: src = Wq; dstoff = 0;    break;
        case 1: src = Wk; dstoff = 384;  break;
        case 2: src = Wv; dstoff = 768;  break;
        case 3: src = Wo; dstoff = 1152; break;
        default: src = Wm; dstoff = 1536;
    }
    src += (size_t)l * E_DIM * E_DIM;
    __hip_bfloat16* dst = WtL + ((size_t)l * 1920 + dstoff) * E_DIM;
    tconv_tile(src, dst, E_DIM, E_DIM, blockIdx.x * 64, blockIdx.y * 64);
}

__global__ __launch_bounds__(256) void tconv_lm(const float* __restrict__ Wlm,
                                                __hip_bfloat16* __restrict__ dst) {
    tconv_tile(Wlm, dst, E_DIM, VOCAB, blockIdx.x * 64, blockIdx.y * 64);
}

// ---------------- bf16 MFMA GEMM (128x128 tile, BK=64, XOR-swizzled LDS) --------
__device__ __forceinline__ void gload16(const void* g, void* l) {
    __builtin_amdgcn_global_load_lds((const __attribute__((address_space(1))) char*)g,
                                     (__attribute__((address_space(3))) char*)l, 16, 0, 0);
}

template <int MODE>
__global__ __launch_bounds__(256) void mgemm(const __hip_bfloat16* __restrict__ A,
                                             const __hip_bfloat16* __restrict__ Bt,
                                             const float* __restrict__ bias,
                                             float* __restrict__ C,
                                             int N, int K) {
    __shared__ __align__(1024) char lds[32768];
    char* Ar = lds;
    char* Br = lds + 16384;
    int tid = threadIdx.x;
    int lane = tid & 63, w = tid >> 6;
    int wm = w >> 1, wn = w & 1;
    int row0 = blockIdx.y * 128;
    int col0 = blockIdx.x * 128;

    f32x4 acc[4][4];
#pragma unroll
    for (int i = 0; i < 4; ++i)
#pragma unroll
        for (int j = 0; j < 4; ++j) acc[i][j] = (f32x4){0.f, 0.f, 0.f, 0.f};

    for (int k0 = 0; k0 < K; k0 += 64) {
        __syncthreads();
#pragma unroll
        for (int i = 0; i < 4; ++i) {
            int p  = i * 4096 + tid * 16;
            int lg = p ^ (((p >> 7) & 7) << 4);
            int r  = lg >> 7, cb = lg & 127;
            gload16((const char*)(A  + (size_t)(row0 + r) * K + k0) + cb, Ar + i * 4096 + w * 1024);
            gload16((const char*)(Bt + (size_t)(col0 + r) * K + k0) + cb, Br + i * 4096 + w * 1024);
        }
        __syncthreads();
#pragma unroll
        for (int ks = 0; ks < 2; ++ks) {
            bf16x8 af[4], bfr[4];
#pragma unroll
            for (int mi = 0; mi < 4; ++mi) {
                int rl = wm * 64 + mi * 16 + (lane & 15);
                int lg = rl * 128 + (ks * 32 + (lane >> 4) * 8) * 2;
                int ph = lg ^ ((rl & 7) << 4);
                af[mi] = *(const bf16x8*)(Ar + ph);
            }
#pragma unroll
            for (int ni = 0; ni < 4; ++ni) {
                int rl = wn * 64 + ni * 16 + (lane & 15);
                int lg = rl * 128 + (ks * 32 + (lane >> 4) * 8) * 2;
                int ph = lg ^ ((rl & 7) << 4);
                bfr[ni] = *(const bf16x8*)(Br + ph);
            }
#pragma unroll
            for (int mi = 0; mi < 4; ++mi)
#pragma unroll
                for (int ni = 0; ni < 4; ++ni)
                    acc[mi][ni] = __builtin_amdgcn_mfma_f32_16x16x32_bf16(
                        af[mi], bfr[ni], acc[mi][ni], 0, 0, 0);
        }
    }

#pragma unroll
    for (int mi = 0; mi < 4; ++mi) {
#pragma unroll
        for (int ni = 0; ni < 4; ++ni) {
            int gr = row0 + wm * 64 + mi * 16 + ((lane >> 4) << 2);
            int gc = col0 + wn * 64 + ni * 16 + (lane & 15);
            if (MODE != 3 || gc < N) {
                float bv = (MODE == 0) ? 0.f : bias[gc];
#pragma unroll
                for (int j = 0; j < 4; ++j) {
                    float* cp = C + (size_t)(gr + j) * N + gc;
                    float v = acc[mi][ni][j];
                    if (MODE == 0)      *cp = v;
                    else if (MODE == 1) *cp = *cp + v + bv;
                    else if (MODE == 2) *cp = *cp + fmaxf(v + bv, 0.f);
                    else                *cp = v + bv;
                }
            }
        }
    }
}

// ---------------- qkv reorg: f32 [4096][1152] -> per-head bf16 Q,K,Vt ----------
__global__ __launch_bounds__(256) void qkv_reorg(const float* __restrict__ qkv,
                                                 __hip_bfloat16* __restrict__ qb,
                                                 __hip_bfloat16* __restrict__ kb,
                                                 __hip_bfloat16* __restrict__ vt) {
    __shared__ __hip_bfloat16 vbuf[64][66];
    int tid = threadIdx.x;
    int bh = blockIdx.x;
    int b = bh / N_HEAD, h = bh - b * N_HEAD;
    const float* base = qkv + (size_t)b * SEQ * QKV_N + h * 64;

    // Q/K: convert + per-head repack (rows of 64, contiguous)
#pragma unroll 4
    for (int i = 0; i < 16; ++i) {
        int id = i * 256 + tid;
        int t = id >> 4, dg = (id & 15) << 2;
        const float* src = base + (size_t)t * QKV_N + dg;
        float4 q4 = *(const float4*)(src);
        float4 k4 = *(const float4*)(src + 384);
        ushort4 qq, kk;
        qq.x = f2bu(q4.x); qq.y = f2bu(q4.y); qq.z = f2bu(q4.z); qq.w = f2bu(q4.w);
        kk.x = f2bu(k4.x); kk.y = f2bu(k4.y); kk.z = f2bu(k4.z); kk.w = f2bu(k4.w);
        *(ushort4*)(qb + ((size_t)bh * SEQ + t) * 64 + dg) = qq;
        *(ushort4*)(kb + ((size_t)bh * SEQ + t) * 64 + dg) = kk;
    }

    // V: transpose to vt[bh][64][256] via LDS (4 chunks of 64 t-rows)
    for (int c = 0; c < 4; ++c) {
        __syncthreads();
        int tl = tid >> 2, db = (tid & 3) << 4;
        const float* vsrc = base + (size_t)(c * 64 + tl) * QKV_N + 768 + db;
#pragma unroll
        for (int u = 0; u < 16; u += 4) {
            float4 v4 = *(const float4*)(vsrc + u);
            vbuf[tl][db + u + 0] = __float2bfloat16(v4.x);
            vbuf[tl][db + u + 1] = __float2bfloat16(v4.y);
            vbuf[tl][db + u + 2] = __float2bfloat16(v4.z);
            vbuf[tl][db + u + 3] = __float2bfloat16(v4.w);
        }
        __syncthreads();
        int dr = tid >> 2, tb = (tid & 3) << 4;
        unsigned short tmp[16];
#pragma unroll
        for (int u = 0; u < 16; ++u) {
            __hip_bfloat16 hv = vbuf[tb + u][dr];
            tmp[u] = *reinterpret_cast<unsigned short*>(&hv);
        }
        ushort8v* dst = (ushort8v*)(vt + ((size_t)bh * 64 + dr) * SEQ + c * 64 + tb);
        dst[0] = *(ushort8v*)(tmp);
        dst[1] = *(ushort8v*)(tmp + 8);
    }
}

// ---------------- fused MFMA attention: block = (bh, 64 q-rows), 4 waves -------
// LDS: K[256][64]bf16 swz | Vt[64][256]bf16 swz | Q[64][64]bf16 swz | P per-wave
#define ATT_K 0
#define ATT_V 32768
#define ATT_Q 65536
#define ATT_P 73728

__global__ __launch_bounds__(256) void attn_fused(const __hip_bfloat16* __restrict__ qb,
                                                  const __hip_bfloat16* __restrict__ kb,
                                                  const __hip_bfloat16* __restrict__ vt,
                                                  __hip_bfloat16* __restrict__ o) {
    __shared__ __align__(1024) char lds[106496];
    int tid = threadIdx.x;
    int lane = tid & 63, w = tid >> 6;
    int bh = blockIdx.x;
    int mq = blockIdx.y;
    int b = bh / N_HEAD, h = bh - b * N_HEAD;

    // stage K: 256 rows x 128B, swizzle byte^=((row&7)<<4) via pre-swizzled source
    const char* kg = (const char*)(kb + (size_t)bh * SEQ * 64);
#pragma unroll
    for (int i = 0; i < 8; ++i) {
        int p = i * 4096 + tid * 16;
        int lg = p ^ (((p >> 7) & 7) << 4);
        gload16(kg + lg, lds + ATT_K + p);
    }
    // stage Vt: 64 rows x 512B, swizzle with row = p>>9
    const char* vg = (const char*)(vt + (size_t)bh * 64 * SEQ);
#pragma unroll
    for (int i = 0; i < 8; ++i) {
        int p = i * 4096 + tid * 16;
        int lg = p ^ (((p >> 9) & 7) << 4);
        gload16(vg + lg, lds + ATT_V + p);
    }
    // stage Q tile: 64 rows x 128B
    const char* qg = (const char*)(qb + ((size_t)bh * SEQ + mq * 64) * 64);
#pragma unroll
    for (int i = 0; i < 2; ++i) {
        int p = i * 4096 + tid * 16;
        int lg = p ^ (((p >> 7) & 7) << 4);
        gload16(qg + lg, lds + ATT_Q + p);
    }
    __syncthreads();

    int q0 = w * 16;             // wave's rows within the 64-row tile
    int qg0 = mq * 64 + q0;      // global q row base

    // ---- QK^T: acc[n] covers cols n*16..n*16+15 for the wave's 16 rows ----
    f32x4 acc[16];
#pragma unroll
    for (int n = 0; n < 16; ++n) acc[n] = (f32x4){0.f, 0.f, 0.f, 0.f};
#pragma unroll
    for (int ks = 0; ks < 2; ++ks) {
        int rq = q0 + (lane & 15);
        int byq = (ks * 64 + ((lane >> 4) << 4)) ^ ((rq & 7) << 4);
        bf16x8 aq = *(const bf16x8*)(lds + ATT_Q + rq * 128 + byq);
#pragma unroll
        for (int n = 0; n < 16; ++n) {
            int rk = n * 16 + (lane & 15);
            int byk = (ks * 64 + ((lane >> 4) << 4)) ^ ((rk & 7) << 4);
            bf16x8 bk = *(const bf16x8*)(lds + ATT_K + rk * 128 + byk);
            acc[n] = __builtin_amdgcn_mfma_f32_16x16x32_bf16(aq, bk, acc[n], 0, 0, 0);
        }
    }

    // ---- causal mask + scale + softmax + write normalized P (bf16, swz LDS) ----
    char* pbase = lds + ATT_P + w * 8192;   // per-wave [16][256] bf16, 512B rows
#pragma unroll
    for (int j = 0; j < 4; ++j) {
        int rql = ((lane >> 4) << 2) + j;    // 0..15
        int rg = qg0 + rql;                  // global row
        float s[16];
        float m = -INFINITY;
#pragma unroll
        for (int n = 0; n < 16; ++n) {
            int cg = n * 16 + (lane & 15);
            float v = (cg <= rg) ? acc[n][j] * 0.125f : -INFINITY;
            s[n] = v;
            m = fmaxf(m, v);
        }
#pragma unroll
        for (int off = 1; off < 16; off <<= 1) m = fmaxf(m, __shfl_xor(m, off));
        float sum = 0.f;
#pragma unroll
        for (int n = 0; n < 16; ++n) { s[n] = __expf(s[n] - m); sum += s[n]; }
#pragma unroll
        for (int off = 1; off < 16; off <<= 1) sum += __shfl_xor(sum, off);
        float inv = 1.0f / sum;
#pragma unroll
        for (int n = 0; n < 16; ++n) {
            int cg = n * 16 + (lane & 15);
            int by = (cg * 2) ^ ((rql & 7) << 4);
            *(__hip_bfloat16*)(pbase + rql * 512 + by) = __float2bfloat16(s[n] * inv);
        }
    }

    // ---- PV: O[16][64] = P[16][256] @ V[256][64] (B from Vt rows) ----
    f32x4 oacc[4];
#pragma unroll
    for (int nf = 0; nf < 4; ++nf) oacc[nf] = (f32x4){0.f, 0.f, 0.f, 0.f};
#pragma unroll
    for (int ks = 0; ks < 8; ++ks) {
        int rp = lane & 15;
        int byp = (ks * 64 + ((lane >> 4) << 4)) ^ ((rp & 7) << 4);
        bf16x8 ap = *(const bf16x8*)(pbase + rp * 512 + byp);
#pragma unroll
        for (int nf = 0; nf < 4; ++nf) {
            int rv = nf * 16 + (lane & 15);
            int byv = (ks * 64 + ((lane >> 4) << 4)) ^ ((rv & 7) << 4);
            bf16x8 bv = *(const bf16x8*)(lds + ATT_V + rv * 512 + byv);
            oacc[nf] = __builtin_amdgcn_mfma_f32_16x16x32_bf16(ap, bv, oacc[nf], 0, 0, 0);
        }
    }

    // ---- store O to hb[b,t,h*64+d] ----
#pragma unroll
    for (int nf = 0; nf < 4; ++nf) {
#pragma unroll
        for (int j = 0; j < 4; ++j) {
            int t = mq * 64 + q0 + ((lane >> 4) << 2) + j;
            int d = nf * 16 + (lane & 15);
            o[(size_t)(b * SEQ + t) * E_DIM + h * 64 + d] = __float2bfloat16(oacc[nf][j]);
        }
    }
}

extern "C" void kernel_launch(void* const* d_in, const int* in_sizes, int n_in,
                              void* d_out, int out_size, void* d_ws, size_t ws_size,
                              hipStream_t stream) {
    const int*   idx  = (const int*)d_in[0];
    const float* tok  = (const float*)d_in[1];
    const float* pos  = (const float*)d_in[2];
    const float* Wq   = (const float*)d_in[3];
    const float* Wk   = (const float*)d_in[4];
    const float* Wv   = (const float*)d_in[5];
    const float* Wo   = (const float*)d_in[6];
    const float* bo   = (const float*)d_in[7];
    const float* ln1g = (const float*)d_in[8];
    const float* ln1b = (const float*)d_in[9];
    const float* ln2g = (const float*)d_in[10];
    const float* ln2b = (const float*)d_in[11];
    const float* Wm   = (const float*)d_in[12];
    const float* bm   = (const float*)d_in[13];
    const float* lnfg = (const float*)d_in[14];
    const float* lnfb = (const float*)d_in[15];
    const float* Wlm  = (const float*)d_in[16];
    const float* blm  = (const float*)d_in[17];
    float* out = (float*)d_out;

    float*           x    = (float*)d_ws;
    __hip_bfloat16*  hb   = (__hip_bfloat16*)(x + (size_t)NTOK * E_DIM);
    float*           qkv  = (float*)(hb + (size_t)NTOK * E_DIM);
    __hip_bfloat16*  WtL  = (__hip_bfloat16*)(qkv + (size_t)NTOK * QKV_N);
    __hip_bfloat16*  WtLM = WtL + (size_t)NLAYER * 1920 * E_DIM;
    __hip_bfloat16*  qbv  = WtLM + (size_t)VPAD * E_DIM;
    __hip_bfloat16*  kbv  = qbv + (size_t)NBH * SEQ * 64;
    __hip_bfloat16*  vtb  = kbv + (size_t)NBH * SEQ * 64;

    embed_kernel<<<(NTOK * E_DIM + 255) / 256, 256, 0, stream>>>(idx, tok, pos, x);
    tconv_layers<<<dim3(6, 6, NLAYER * 5), 256, 0, stream>>>(Wq, Wk, Wv, Wo, Wm, WtL);
    tconv_lm<<<dim3(VPAD / 64, E_DIM / 64), 256, 0, stream>>>(Wlm, WtLM);

    for (int l = 0; l < NLAYER; ++l) {
        const __hip_bfloat16* wl = WtL + (size_t)l * 1920 * E_DIM;
        ln_kernel<<<NTOK / 4, 256, 0, stream>>>(x, ln1g + l * E_DIM, ln1b + l * E_DIM, hb);
        mgemm<0><<<dim3(QKV_N / 128, NTOK / 128), 256, 0, stream>>>(hb, wl, nullptr, qkv, QKV_N, E_DIM);
        qkv_reorg<<<NBH, 256, 0, stream>>>(qkv, qbv, kbv, vtb);
        attn_fused<<<dim3(NBH, 4), 256, 0, stream>>>(qbv, kbv, vtb, hb);
        mgemm<1><<<dim3(E_DIM / 128, NTOK / 128), 256, 0, stream>>>(hb, wl + (size_t)1152 * E_DIM,
                                                                    bo + l * E_DIM, x, E_DIM, E_DIM);
        ln_kernel<<<NTOK / 4, 256, 0, stream>>>(x, ln2g + l * E_DIM, ln2b + l * E_DIM, hb);
        mgemm<2><<<dim3(E_DIM / 128, NTOK / 128), 256, 0, stream>>>(hb, wl + (size_t)1536 * E_DIM,
                                                                    bm + l * E_DIM, x, E_DIM, E_DIM);
    }
    ln_kernel<<<NTOK / 4, 256, 0, stream>>>(x, lnfg, lnfb, hb);

    mgemm<3><<<dim3(VPAD / 128, NTOK / 128), 256, 0, stream>>>(hb, WtLM, blm, out, VOCAB, E_DIM);
}

// Round 4
// 866.456 us; speedup vs baseline: 5.7711x; 1.1463x over previous
//
#include <hip/hip_runtime.h>
#include <hip/hip_bf16.h>
#include <math.h>

#define E_DIM 384
#define N_HEAD 6
#define HEAD_SZ 64
#define SEQ 256
#define BATCH 16
#define NTOK 4096
#define NLAYER 6
#define VOCAB 50257
#define VPAD 50304          // 393*128
#define QKV_N 1152          // 3*E
#define NBH 96              // BATCH*N_HEAD

typedef __attribute__((ext_vector_type(8))) short bf16x8;
typedef __attribute__((ext_vector_type(4))) float f32x4;

__device__ __forceinline__ void gload16(const void* g, void* l) {
    __builtin_amdgcn_global_load_lds((const __attribute__((address_space(1))) char*)g,
                                     (__attribute__((address_space(3))) char*)l, 16, 0, 0);
}

// ---------------- embedding ----------------
__global__ void embed_kernel(const int* __restrict__ idx,
                             const float* __restrict__ tok,
                             const float* __restrict__ pos,
                             float* __restrict__ x) {
    int i = blockIdx.x * blockDim.x + threadIdx.x;
    if (i >= NTOK * E_DIM) return;
    int m = i / E_DIM, e = i - m * E_DIM;
    int t = m & (SEQ - 1);
    x[i] = tok[(size_t)idx[m] * E_DIM + e] + pos[t * E_DIM + e];
}

// ---------------- layernorm (used once, after embed) ----------------
__global__ __launch_bounds__(256) void ln_kernel(const float* __restrict__ x,
                                                 const float* __restrict__ g,
                                                 const float* __restrict__ b,
                                                 __hip_bfloat16* __restrict__ h) {
    int lane = threadIdx.x & 63;
    int wave = threadIdx.x >> 6;
    int row  = blockIdx.x * 4 + wave;
    const float* xr = x + (size_t)row * E_DIM;
    float v[6];
    float s = 0.f;
#pragma unroll
    for (int c = 0; c < 6; ++c) { v[c] = xr[lane + 64 * c]; s += v[c]; }
#pragma unroll
    for (int off = 32; off > 0; off >>= 1) s += __shfl_xor(s, off);
    float mu = s * (1.0f / E_DIM);
    float s2 = 0.f;
#pragma unroll
    for (int c = 0; c < 6; ++c) { float d = v[c] - mu; s2 += d * d; }
#pragma unroll
    for (int off = 32; off > 0; off >>= 1) s2 += __shfl_xor(s2, off);
    float rstd = rsqrtf(s2 * (1.0f / E_DIM) + 1e-5f);
    __hip_bfloat16* hr = h + (size_t)row * E_DIM;
#pragma unroll
    for (int c = 0; c < 6; ++c) {
        int e = lane + 64 * c;
        hr[e] = __float2bfloat16((v[c] - mu) * rstd * g[e] + b[e]);
    }
}

// ---------------- weight transpose + f32->bf16 convert ----------------
__device__ __forceinline__ void tconv_tile(const float* __restrict__ src,
                                           __hip_bfloat16* __restrict__ dst,
                                           int K, int N, int n0, int k0) {
    __shared__ float tbuf[64][65];
    int c = threadIdx.x & 63, r4 = threadIdx.x >> 6;
#pragma unroll
    for (int i = 0; i < 16; ++i) {
        int r = r4 * 16 + i;
        float v = 0.f;
        if (n0 + c < N) v = src[(size_t)(k0 + r) * N + n0 + c];
        tbuf[r][c] = v;
    }
    __syncthreads();
#pragma unroll
    for (int i = 0; i < 16; ++i) {
        int rn = r4 * 16 + i;
        dst[(size_t)(n0 + rn) * K + k0 + c] = __float2bfloat16(tbuf[c][rn]);
    }
}

__global__ __launch_bounds__(256) void tconv_layers(const float* __restrict__ Wq,
                                                    const float* __restrict__ Wk,
                                                    const float* __restrict__ Wv,
                                                    const float* __restrict__ Wo,
                                                    const float* __restrict__ Wm,
                                                    __hip_bfloat16* __restrict__ WtL) {
    int z = blockIdx.z;
    int l = z / 5, t = z - l * 5;
    const float* src;
    int dstoff;
    switch (t) {
        case 0: src = Wq; dstoff = 0;    break;
        case 1: src = Wk; dstoff = 384;  break;
        case 2: src = Wv; dstoff = 768;  break;
        case 3: src = Wo; dstoff = 1152; break;
        default: src = Wm; dstoff = 1536;
    }
    src += (size_t)l * E_DIM * E_DIM;
    __hip_bfloat16* dst = WtL + ((size_t)l * 1920 + dstoff) * E_DIM;
    tconv_tile(src, dst, E_DIM, E_DIM, blockIdx.x * 64, blockIdx.y * 64);
}

__global__ __launch_bounds__(256) void tconv_lm(const float* __restrict__ Wlm,
                                                __hip_bfloat16* __restrict__ dst) {
    tconv_tile(Wlm, dst, E_DIM, VOCAB, blockIdx.x * 64, blockIdx.y * 64);
}

// ---------------- QKV GEMM: [4096][384]bf16 @ WqkvT -> per-head Q,K,Vt bf16 ------
// 128x128 tile. Each col-block covers exactly 2 heads of one of Q/K/V.
__global__ __launch_bounds__(256) void qkvgemm(const __hip_bfloat16* __restrict__ A,
                                               const __hip_bfloat16* __restrict__ Bt,
                                               __hip_bfloat16* __restrict__ qb,
                                               __hip_bfloat16* __restrict__ kb,
                                               __hip_bfloat16* __restrict__ vt) {
    __shared__ __align__(1024) char lds[32768];
    char* Ar = lds;
    char* Br = lds + 16384;
    int tid = threadIdx.x;
    int lane = tid & 63, w = tid >> 6;
    int wm = w >> 1, wn = w & 1;
    int row0 = blockIdx.y * 128;
    int col0 = blockIdx.x * 128;

    f32x4 acc[4][4];
#pragma unroll
    for (int i = 0; i < 4; ++i)
#pragma unroll
        for (int j = 0; j < 4; ++j) acc[i][j] = (f32x4){0.f, 0.f, 0.f, 0.f};

    for (int k0 = 0; k0 < E_DIM; k0 += 64) {
        __syncthreads();
#pragma unroll
        for (int i = 0; i < 4; ++i) {
            int p  = i * 4096 + tid * 16;
            int lg = p ^ (((p >> 7) & 7) << 4);
            int r  = lg >> 7, cb = lg & 127;
            gload16((const char*)(A  + (size_t)(row0 + r) * E_DIM + k0) + cb, Ar + i * 4096 + w * 1024);
            gload16((const char*)(Bt + (size_t)(col0 + r) * E_DIM + k0) + cb, Br + i * 4096 + w * 1024);
        }
        __syncthreads();
#pragma unroll
        for (int ks = 0; ks < 2; ++ks) {
            bf16x8 af[4], bfr[4];
#pragma unroll
            for (int mi = 0; mi < 4; ++mi) {
                int rl = wm * 64 + mi * 16 + (lane & 15);
                int lg = rl * 128 + ks * 64 + ((lane >> 4) << 4);
                int ph = lg ^ ((rl & 7) << 4);
                af[mi] = *(const bf16x8*)(Ar + ph);
            }
#pragma unroll
            for (int ni = 0; ni < 4; ++ni) {
                int rl = wn * 64 + ni * 16 + (lane & 15);
                int lg = rl * 128 + ks * 64 + ((lane >> 4) << 4);
                int ph = lg ^ ((rl & 7) << 4);
                bfr[ni] = *(const bf16x8*)(Br + ph);
            }
#pragma unroll
            for (int mi = 0; mi < 4; ++mi)
#pragma unroll
                for (int ni = 0; ni < 4; ++ni)
                    acc[mi][ni] = __builtin_amdgcn_mfma_f32_16x16x32_bf16(
                        af[mi], bfr[ni], acc[mi][ni], 0, 0, 0);
        }
    }

#pragma unroll
    for (int mi = 0; mi < 4; ++mi) {
#pragma unroll
        for (int ni = 0; ni < 4; ++ni) {
            int gcl = col0 + wn * 64 + ni * 16 + (lane & 15);   // 0..1151
            int which = gcl / 384;
            int rem = gcl - which * 384;
            int h = rem >> 6, d = rem & 63;
            int gr0 = row0 + wm * 64 + mi * 16 + ((lane >> 4) << 2);
#pragma unroll
            for (int j = 0; j < 4; ++j) {
                int gr = gr0 + j;
                int b = gr >> 8, t = gr & 255;
                int bh = b * N_HEAD + h;
                __hip_bfloat16 v = __float2bfloat16(acc[mi][ni][j]);
                if (which == 0)      qb[(((size_t)bh << 8) + t) * 64 + d] = v;
                else if (which == 1) kb[(((size_t)bh << 8) + t) * 64 + d] = v;
                else                 vt[(((size_t)bh << 6) + d) * SEQ + t] = v;
            }
        }
    }
}

// ---------------- fused GEMM + residual + LayerNorm ----------------
// tile 32 rows x 384 cols (full E), 4 waves (1x4), grid 128 blocks.
// xnew = xin + (RELU? relu(AB+bias) : AB+bias); xout=xnew; hout=LN(xnew; g,b)
template <int RELU>
__global__ __launch_bounds__(256) void egemm_ln(const __hip_bfloat16* __restrict__ A,
                                                const __hip_bfloat16* __restrict__ Bt,
                                                const float* __restrict__ bias,
                                                const float* __restrict__ xin,
                                                float* __restrict__ xout,
                                                const float* __restrict__ g,
                                                const float* __restrict__ bvec,
                                                __hip_bfloat16* __restrict__ hout) {
    __shared__ __align__(1024) char lds[53248];   // B[0,48K) + A[48K,52K); xt aliases after loop
    char* Breg = lds;
    char* Areg = lds + 49152;
    float* xt = (float*)lds;                      // [32][392] f32
    int tid = threadIdx.x;
    int lane = tid & 63, w = tid >> 6;            // wn = w (1x4)
    int row0 = blockIdx.x * 32;

    f32x4 acc[2][6];
#pragma unroll
    for (int i = 0; i < 2; ++i)
#pragma unroll
        for (int j = 0; j < 6; ++j) acc[i][j] = (f32x4){0.f, 0.f, 0.f, 0.f};

    for (int k0 = 0; k0 < E_DIM; k0 += 64) {
        __syncthreads();
        {   // A: 32 rows x 128B
            int p  = tid * 16;
            int lg = p ^ (((p >> 7) & 7) << 4);
            int r  = lg >> 7, cb = lg & 127;
            gload16((const char*)(A + (size_t)(row0 + r) * E_DIM + k0) + cb, Areg + w * 1024);
        }
#pragma unroll
        for (int i = 0; i < 12; ++i) {   // B: 384 rows x 128B
            int p  = i * 4096 + tid * 16;
            int lg = p ^ (((p >> 7) & 7) << 4);
            int r  = lg >> 7, cb = lg & 127;
            gload16((const char*)(Bt + (size_t)r * E_DIM + k0) + cb, Breg + i * 4096 + w * 1024);
        }
        __syncthreads();
#pragma unroll
        for (int ks = 0; ks < 2; ++ks) {
            bf16x8 af[2], bfr[6];
#pragma unroll
            for (int mi = 0; mi < 2; ++mi) {
                int rl = mi * 16 + (lane & 15);
                int lg = rl * 128 + ks * 64 + ((lane >> 4) << 4);
                int ph = lg ^ ((rl & 7) << 4);
                af[mi] = *(const bf16x8*)(Areg + ph);
            }
#pragma unroll
            for (int ni = 0; ni < 6; ++ni) {
                int rl = w * 96 + ni * 16 + (lane & 15);
                int lg = rl * 128 + ks * 64 + ((lane >> 4) << 4);
                int ph = lg ^ ((rl & 7) << 4);
                bfr[ni] = *(const bf16x8*)(Breg + ph);
            }
#pragma unroll
            for (int mi = 0; mi < 2; ++mi)
#pragma unroll
                for (int ni = 0; ni < 6; ++ni)
                    acc[mi][ni] = __builtin_amdgcn_mfma_f32_16x16x32_bf16(
                        af[mi], bfr[ni], acc[mi][ni], 0, 0, 0);
        }
    }
    __syncthreads();   // all frag reads done before xt overwrites staging

    // residual + bias (+relu), write xout and LDS tile
#pragma unroll
    for (int mi = 0; mi < 2; ++mi) {
#pragma unroll
        for (int ni = 0; ni < 6; ++ni) {
            int gc = w * 96 + ni * 16 + (lane & 15);
            int lr0 = mi * 16 + ((lane >> 4) << 2);
            float bv = bias[gc];
#pragma unroll
            for (int j = 0; j < 4; ++j) {
                int lr = lr0 + j;
                float u = acc[mi][ni][j] + bv;
                if (RELU) u = fmaxf(u, 0.f);
                float xn = xin[(size_t)(row0 + lr) * E_DIM + gc] + u;
                xout[(size_t)(row0 + lr) * E_DIM + gc] = xn;
                xt[lr * 392 + gc] = xn;
            }
        }
    }
    __syncthreads();

    // LayerNorm: 8 rows per wave
#pragma unroll
    for (int r8 = 0; r8 < 8; ++r8) {
        int r = w * 8 + r8;
        float v[6];
        float s = 0.f;
#pragma unroll
        for (int c = 0; c < 6; ++c) { v[c] = xt[r * 392 + lane + 64 * c]; s += v[c]; }
#pragma unroll
        for (int off = 32; off > 0; off >>= 1) s += __shfl_xor(s, off);
        float mu = s * (1.0f / E_DIM);
        float s2 = 0.f;
#pragma unroll
        for (int c = 0; c < 6; ++c) { float d = v[c] - mu; s2 += d * d; }
#pragma unroll
        for (int off = 32; off > 0; off >>= 1) s2 += __shfl_xor(s2, off);
        float rstd = rsqrtf(s2 * (1.0f / E_DIM) + 1e-5f);
        __hip_bfloat16* hr = hout + (size_t)(row0 + r) * E_DIM;
#pragma unroll
        for (int c = 0; c < 6; ++c) {
            int e = lane + 64 * c;
            hr[e] = __float2bfloat16((v[c] - mu) * rstd * g[e] + bvec[e]);
        }
    }
}

// ---------------- LM-head GEMM (128x128, XOR-swizzled LDS) ----------------
__global__ __launch_bounds__(256) void mgemm_lm(const __hip_bfloat16* __restrict__ A,
                                                const __hip_bfloat16* __restrict__ Bt,
                                                const float* __restrict__ bias,
                                                float* __restrict__ C) {
    __shared__ __align__(1024) char lds[32768];
    char* Ar = lds;
    char* Br = lds + 16384;
    int tid = threadIdx.x;
    int lane = tid & 63, w = tid >> 6;
    int wm = w >> 1, wn = w & 1;
    int row0 = blockIdx.y * 128;
    int col0 = blockIdx.x * 128;

    f32x4 acc[4][4];
#pragma unroll
    for (int i = 0; i < 4; ++i)
#pragma unroll
        for (int j = 0; j < 4; ++j) acc[i][j] = (f32x4){0.f, 0.f, 0.f, 0.f};

    for (int k0 = 0; k0 < E_DIM; k0 += 64) {
        __syncthreads();
#pragma unroll
        for (int i = 0; i < 4; ++i) {
            int p  = i * 4096 + tid * 16;
            int lg = p ^ (((p >> 7) & 7) << 4);
            int r  = lg >> 7, cb = lg & 127;
            gload16((const char*)(A  + (size_t)(row0 + r) * E_DIM + k0) + cb, Ar + i * 4096 + w * 1024);
            gload16((const char*)(Bt + (size_t)(col0 + r) * E_DIM + k0) + cb, Br + i * 4096 + w * 1024);
        }
        __syncthreads();
#pragma unroll
        for (int ks = 0; ks < 2; ++ks) {
            bf16x8 af[4], bfr[4];
#pragma unroll
            for (int mi = 0; mi < 4; ++mi) {
                int rl = wm * 64 + mi * 16 + (lane & 15);
                int lg = rl * 128 + ks * 64 + ((lane >> 4) << 4);
                int ph = lg ^ ((rl & 7) << 4);
                af[mi] = *(const bf16x8*)(Ar + ph);
            }
#pragma unroll
            for (int ni = 0; ni < 4; ++ni) {
                int rl = wn * 64 + ni * 16 + (lane & 15);
                int lg = rl * 128 + ks * 64 + ((lane >> 4) << 4);
                int ph = lg ^ ((rl & 7) << 4);
                bfr[ni] = *(const bf16x8*)(Br + ph);
            }
#pragma unroll
            for (int mi = 0; mi < 4; ++mi)
#pragma unroll
                for (int ni = 0; ni < 4; ++ni)
                    acc[mi][ni] = __builtin_amdgcn_mfma_f32_16x16x32_bf16(
                        af[mi], bfr[ni], acc[mi][ni], 0, 0, 0);
        }
    }

#pragma unroll
    for (int mi = 0; mi < 4; ++mi) {
#pragma unroll
        for (int ni = 0; ni < 4; ++ni) {
            int gr = row0 + wm * 64 + mi * 16 + ((lane >> 4) << 2);
            int gc = col0 + wn * 64 + ni * 16 + (lane & 15);
            if (gc < VOCAB) {
                float bv = bias[gc];
#pragma unroll
                for (int j = 0; j < 4; ++j)
                    C[(size_t)(gr + j) * VOCAB + gc] = acc[mi][ni][j] + bv;
            }
        }
    }
}

// ---------------- fused MFMA attention (72 KB LDS, P aliases K) -------
#define ATT_K 0
#define ATT_V 32768
#define ATT_Q 65536

__global__ __launch_bounds__(256) void attn_fused(const __hip_bfloat16* __restrict__ qb,
                                                  const __hip_bfloat16* __restrict__ kb,
                                                  const __hip_bfloat16* __restrict__ vt,
                                                  __hip_bfloat16* __restrict__ o) {
    __shared__ __align__(1024) char lds[73728];
    int tid = threadIdx.x;
    int lane = tid & 63, w = tid >> 6;
    int bh = blockIdx.x;
    int mq = blockIdx.y;
    int b = bh / N_HEAD, h = bh - b * N_HEAD;

    const char* kg = (const char*)(kb + (size_t)bh * SEQ * 64);
#pragma unroll
    for (int i = 0; i < 8; ++i) {
        int p = i * 4096 + tid * 16;
        int lg = p ^ (((p >> 7) & 7) << 4);
        gload16(kg + lg, lds + ATT_K + p);
    }
    const char* vg = (const char*)(vt + (size_t)bh * 64 * SEQ);
#pragma unroll
    for (int i = 0; i < 8; ++i) {
        int p = i * 4096 + tid * 16;
        int lg = p ^ (((p >> 9) & 7) << 4);
        gload16(vg + lg, lds + ATT_V + p);
    }
    const char* qg = (const char*)(qb + ((size_t)bh * SEQ + mq * 64) * 64);
#pragma unroll
    for (int i = 0; i < 2; ++i) {
        int p = i * 4096 + tid * 16;
        int lg = p ^ (((p >> 7) & 7) << 4);
        gload16(qg + lg, lds + ATT_Q + p);
    }
    __syncthreads();

    int q0 = w * 16;
    int qg0 = mq * 64 + q0;

    f32x4 acc[16];
#pragma unroll
    for (int n = 0; n < 16; ++n) acc[n] = (f32x4){0.f, 0.f, 0.f, 0.f};
#pragma unroll
    for (int ks = 0; ks < 2; ++ks) {
        int rq = q0 + (lane & 15);
        int byq = (ks * 64 + ((lane >> 4) << 4)) ^ ((rq & 7) << 4);
        bf16x8 aq = *(const bf16x8*)(lds + ATT_Q + rq * 128 + byq);
#pragma unroll
        for (int n = 0; n < 16; ++n) {
            int rk = n * 16 + (lane & 15);
            int byk = (ks * 64 + ((lane >> 4) << 4)) ^ ((rk & 7) << 4);
            bf16x8 bk = *(const bf16x8*)(lds + ATT_K + rk * 128 + byk);
            acc[n] = __builtin_amdgcn_mfma_f32_16x16x32_bf16(aq, bk, acc[n], 0, 0, 0);
        }
    }
    __syncthreads();   // all K reads done; P may overwrite K region

    char* pbase = lds + ATT_K + w * 8192;   // per-wave [16][256] bf16
#pragma unroll
    for (int j = 0; j < 4; ++j) {
        int rql = ((lane >> 4) << 2) + j;
        int rg = qg0 + rql;
        float s[16];
        float m = -INFINITY;
#pragma unroll
        for (int n = 0; n < 16; ++n) {
            int cg = n * 16 + (lane & 15);
            float v = (cg <= rg) ? acc[n][j] * 0.125f : -INFINITY;
            s[n] = v;
            m = fmaxf(m, v);
        }
#pragma unroll
        for (int off = 1; off < 16; off <<= 1) m = fmaxf(m, __shfl_xor(m, off));
        float sum = 0.f;
#pragma unroll
        for (int n = 0; n < 16; ++n) { s[n] = __expf(s[n] - m); sum += s[n]; }
#pragma unroll
        for (int off = 1; off < 16; off <<= 1) sum += __shfl_xor(sum, off);
        float inv = 1.0f / sum;
#pragma unroll
        for (int n = 0; n < 16; ++n) {
            int cg = n * 16 + (lane & 15);
            int by = (cg * 2) ^ ((rql & 7) << 4);
            *(__hip_bfloat16*)(pbase + rql * 512 + by) = __float2bfloat16(s[n] * inv);
        }
    }

    f32x4 oacc[4];
#pragma unroll
    for (int nf = 0; nf < 4; ++nf) oacc[nf] = (f32x4){0.f, 0.f, 0.f, 0.f};
#pragma unroll
    for (int ks = 0; ks < 8; ++ks) {
        int rp = lane & 15;
        int byp = (ks * 64 + ((lane >> 4) << 4)) ^ ((rp & 7) << 4);
        bf16x8 ap = *(const bf16x8*)(pbase + rp * 512 + byp);
#pragma unroll
        for (int nf = 0; nf < 4; ++nf) {
            int rv = nf * 16 + (lane & 15);
            int byv = (ks * 64 + ((lane >> 4) << 4)) ^ ((rv & 7) << 4);
            bf16x8 bv = *(const bf16x8*)(lds + ATT_V + rv * 512 + byv);
            oacc[nf] = __builtin_amdgcn_mfma_f32_16x16x32_bf16(ap, bv, oacc[nf], 0, 0, 0);
        }
    }

#pragma unroll
    for (int nf = 0; nf < 4; ++nf) {
#pragma unroll
        for (int j = 0; j < 4; ++j) {
            int t = mq * 64 + q0 + ((lane >> 4) << 2) + j;
            int d = nf * 16 + (lane & 15);
            o[(size_t)(b * SEQ + t) * E_DIM + h * 64 + d] = __float2bfloat16(oacc[nf][j]);
        }
    }
}

extern "C" void kernel_launch(void* const* d_in, const int* in_sizes, int n_in,
                              void* d_out, int out_size, void* d_ws, size_t ws_size,
                              hipStream_t stream) {
    const int*   idx  = (const int*)d_in[0];
    const float* tok  = (const float*)d_in[1];
    const float* pos  = (const float*)d_in[2];
    const float* Wq   = (const float*)d_in[3];
    const float* Wk   = (const float*)d_in[4];
    const float* Wv   = (const float*)d_in[5];
    const float* Wo   = (const float*)d_in[6];
    const float* bo   = (const float*)d_in[7];
    const float* ln1g = (const float*)d_in[8];
    const float* ln1b = (const float*)d_in[9];
    const float* ln2g = (const float*)d_in[10];
    const float* ln2b = (const float*)d_in[11];
    const float* Wm   = (const float*)d_in[12];
    const float* bm   = (const float*)d_in[13];
    const float* lnfg = (const float*)d_in[14];
    const float* lnfb = (const float*)d_in[15];
    const float* Wlm  = (const float*)d_in[16];
    const float* blm  = (const float*)d_in[17];
    float* out = (float*)d_out;

    float*           x    = (float*)d_ws;                         // [4096][384] f32
    __hip_bfloat16*  hb   = (__hip_bfloat16*)(x + (size_t)NTOK * E_DIM);
    __hip_bfloat16*  WtL  = hb + (size_t)NTOK * E_DIM;
    __hip_bfloat16*  WtLM = WtL + (size_t)NLAYER * 1920 * E_DIM;  // [50304][384]
    __hip_bfloat16*  qbv  = WtLM + (size_t)VPAD * E_DIM;
    __hip_bfloat16*  kbv  = qbv + (size_t)NBH * SEQ * 64;
    __hip_bfloat16*  vtb  = kbv + (size_t)NBH * SEQ * 64;

    embed_kernel<<<(NTOK * E_DIM + 255) / 256, 256, 0, stream>>>(idx, tok, pos, x);
    tconv_layers<<<dim3(6, 6, NLAYER * 5), 256, 0, stream>>>(Wq, Wk, Wv, Wo, Wm, WtL);
    tconv_lm<<<dim3(VPAD / 64, E_DIM / 64), 256, 0, stream>>>(Wlm, WtLM);
    ln_kernel<<<NTOK / 4, 256, 0, stream>>>(x, ln1g, ln1b, hb);

    for (int l = 0; l < NLAYER; ++l) {
        const __hip_bfloat16* wl = WtL + (size_t)l * 1920 * E_DIM;
        qkvgemm<<<dim3(QKV_N / 128, NTOK / 128), 256, 0, stream>>>(hb, wl, qbv, kbv, vtb);
        attn_fused<<<dim3(NBH, 4), 256, 0, stream>>>(qbv, kbv, vtb, hb);
        egemm_ln<0><<<NTOK / 32, 256, 0, stream>>>(hb, wl + (size_t)1152 * E_DIM,
                                                   bo + l * E_DIM, x, x,
                                                   ln2g + l * E_DIM, ln2b + l * E_DIM, hb);
        const float* ng = (l == NLAYER - 1) ? lnfg : ln1g + (l + 1) * E_DIM;
        const float* nb = (l == NLAYER - 1) ? lnfb : ln1b + (l + 1) * E_DIM;
        egemm_ln<1><<<NTOK / 32, 256, 0, stream>>>(hb, wl + (size_t)1536 * E_DIM,
                                                   bm + l * E_DIM, x, x,
                                                   ng, nb, hb);
    }

    mgemm_lm<<<dim3(VPAD / 128, NTOK / 128), 256, 0, stream>>>(hb, WtLM, blm, out);
}

// Round 5
// 754.715 us; speedup vs baseline: 6.6256x; 1.1481x over previous
//
#include <hip/hip_runtime.h>
#include <hip/hip_bf16.h>
#include <math.h>

#define E_DIM 384
#define N_HEAD 6
#define HEAD_SZ 64
#define SEQ 256
#define BATCH 16
#define NTOK 4096
#define NLAYER 6
#define VOCAB 50257
#define VPAD 50304          // 393*128
#define QKV_N 1152          // 3*E
#define NBH 96              // BATCH*N_HEAD

typedef __attribute__((ext_vector_type(8))) short bf16x8;
typedef __attribute__((ext_vector_type(4))) float f32x4;

__device__ __forceinline__ void gload16(const void* g, void* l) {
    __builtin_amdgcn_global_load_lds((const __attribute__((address_space(1))) char*)g,
                                     (__attribute__((address_space(3))) char*)l, 16, 0, 0);
}

// ---------------- embedding ----------------
__global__ void embed_kernel(const int* __restrict__ idx,
                             const float* __restrict__ tok,
                             const float* __restrict__ pos,
                             float* __restrict__ x) {
    int i = blockIdx.x * blockDim.x + threadIdx.x;
    if (i >= NTOK * E_DIM) return;
    int m = i / E_DIM, e = i - m * E_DIM;
    int t = m & (SEQ - 1);
    x[i] = tok[(size_t)idx[m] * E_DIM + e] + pos[t * E_DIM + e];
}

// ---------------- layernorm (used once, after embed) ----------------
__global__ __launch_bounds__(256) void ln_kernel(const float* __restrict__ x,
                                                 const float* __restrict__ g,
                                                 const float* __restrict__ b,
                                                 __hip_bfloat16* __restrict__ h) {
    int lane = threadIdx.x & 63;
    int wave = threadIdx.x >> 6;
    int row  = blockIdx.x * 4 + wave;
    const float* xr = x + (size_t)row * E_DIM;
    float v[6];
    float s = 0.f;
#pragma unroll
    for (int c = 0; c < 6; ++c) { v[c] = xr[lane + 64 * c]; s += v[c]; }
#pragma unroll
    for (int off = 32; off > 0; off >>= 1) s += __shfl_xor(s, off);
    float mu = s * (1.0f / E_DIM);
    float s2 = 0.f;
#pragma unroll
    for (int c = 0; c < 6; ++c) { float d = v[c] - mu; s2 += d * d; }
#pragma unroll
    for (int off = 32; off > 0; off >>= 1) s2 += __shfl_xor(s2, off);
    float rstd = rsqrtf(s2 * (1.0f / E_DIM) + 1e-5f);
    __hip_bfloat16* hr = h + (size_t)row * E_DIM;
#pragma unroll
    for (int c = 0; c < 6; ++c) {
        int e = lane + 64 * c;
        hr[e] = __float2bfloat16((v[c] - mu) * rstd * g[e] + b[e]);
    }
}

// ---------------- weight transpose + f32->bf16 convert ----------------
__device__ __forceinline__ void tconv_tile(const float* __restrict__ src,
                                           __hip_bfloat16* __restrict__ dst,
                                           int K, int N, int n0, int k0) {
    __shared__ float tbuf[64][65];
    int c = threadIdx.x & 63, r4 = threadIdx.x >> 6;
#pragma unroll
    for (int i = 0; i < 16; ++i) {
        int r = r4 * 16 + i;
        float v = 0.f;
        if (n0 + c < N) v = src[(size_t)(k0 + r) * N + n0 + c];
        tbuf[r][c] = v;
    }
    __syncthreads();
#pragma unroll
    for (int i = 0; i < 16; ++i) {
        int rn = r4 * 16 + i;
        dst[(size_t)(n0 + rn) * K + k0 + c] = __float2bfloat16(tbuf[c][rn]);
    }
}

__global__ __launch_bounds__(256) void tconv_layers(const float* __restrict__ Wq,
                                                    const float* __restrict__ Wk,
                                                    const float* __restrict__ Wv,
                                                    const float* __restrict__ Wo,
                                                    const float* __restrict__ Wm,
                                                    __hip_bfloat16* __restrict__ WtL) {
    int z = blockIdx.z;
    int l = z / 5, t = z - l * 5;
    const float* src;
    int dstoff;
    switch (t) {
        case 0: src = Wq; dstoff = 0;    break;
        case 1: src = Wk; dstoff = 384;  break;
        case 2: src = Wv; dstoff = 768;  break;
        case 3: src = Wo; dstoff = 1152; break;
        default: src = Wm; dstoff = 1536;
    }
    src += (size_t)l * E_DIM * E_DIM;
    __hip_bfloat16* dst = WtL + ((size_t)l * 1920 + dstoff) * E_DIM;
    tconv_tile(src, dst, E_DIM, E_DIM, blockIdx.x * 64, blockIdx.y * 64);
}

__global__ __launch_bounds__(256) void tconv_lm(const float* __restrict__ Wlm,
                                                __hip_bfloat16* __restrict__ dst) {
    tconv_tile(Wlm, dst, E_DIM, VOCAB, blockIdx.x * 64, blockIdx.y * 64);
}

// ---------------- QKV GEMM (issue-early double-buffered staging) ------
// [4096][384]bf16 @ WqkvT -> per-head Q,K,Vt bf16. 128x128 tile.
__global__ __launch_bounds__(256) void qkvgemm(const __hip_bfloat16* __restrict__ A,
                                               const __hip_bfloat16* __restrict__ Bt,
                                               __hip_bfloat16* __restrict__ qb,
                                               __hip_bfloat16* __restrict__ kb,
                                               __hip_bfloat16* __restrict__ vt) {
    __shared__ __align__(1024) char lds[65536];   // [buf][A 16K | B 16K]
    int tid = threadIdx.x;
    int lane = tid & 63, w = tid >> 6;
    int wm = w >> 1, wn = w & 1;
    int row0 = blockIdx.y * 128;
    int col0 = blockIdx.x * 128;

    f32x4 acc[4][4];
#pragma unroll
    for (int i = 0; i < 4; ++i)
#pragma unroll
        for (int j = 0; j < 4; ++j) acc[i][j] = (f32x4){0.f, 0.f, 0.f, 0.f};

    auto stage = [&](int buf, int k0) {
        char* Ab = lds + buf * 32768;
        char* Bb = Ab + 16384;
#pragma unroll
        for (int i = 0; i < 4; ++i) {
            int p  = i * 4096 + tid * 16;
            int lg = p ^ (((p >> 7) & 7) << 4);
            int r  = lg >> 7, cb = lg & 127;
            gload16((const char*)(A  + (size_t)(row0 + r) * E_DIM + k0) + cb, Ab + i * 4096 + w * 1024);
            gload16((const char*)(Bt + (size_t)(col0 + r) * E_DIM + k0) + cb, Bb + i * 4096 + w * 1024);
        }
    };

    stage(0, 0);
    for (int kt = 0; kt < 6; ++kt) {
        __syncthreads();                    // buf[kt&1] landed; prev compute done
        if (kt < 5) stage((kt + 1) & 1, (kt + 1) * 64);   // in-flight during compute
        const char* Ab = lds + (kt & 1) * 32768;
        const char* Bb = Ab + 16384;
#pragma unroll
        for (int ks = 0; ks < 2; ++ks) {
            bf16x8 af[4], bfr[4];
#pragma unroll
            for (int mi = 0; mi < 4; ++mi) {
                int rl = wm * 64 + mi * 16 + (lane & 15);
                int lg = rl * 128 + ks * 64 + ((lane >> 4) << 4);
                int ph = lg ^ ((rl & 7) << 4);
                af[mi] = *(const bf16x8*)(Ab + ph);
            }
#pragma unroll
            for (int ni = 0; ni < 4; ++ni) {
                int rl = wn * 64 + ni * 16 + (lane & 15);
                int lg = rl * 128 + ks * 64 + ((lane >> 4) << 4);
                int ph = lg ^ ((rl & 7) << 4);
                bfr[ni] = *(const bf16x8*)(Bb + ph);
            }
#pragma unroll
            for (int mi = 0; mi < 4; ++mi)
#pragma unroll
                for (int ni = 0; ni < 4; ++ni)
                    acc[mi][ni] = __builtin_amdgcn_mfma_f32_16x16x32_bf16(
                        af[mi], bfr[ni], acc[mi][ni], 0, 0, 0);
        }
    }

#pragma unroll
    for (int mi = 0; mi < 4; ++mi) {
#pragma unroll
        for (int ni = 0; ni < 4; ++ni) {
            int gcl = col0 + wn * 64 + ni * 16 + (lane & 15);   // 0..1151
            int which = gcl / 384;
            int rem = gcl - which * 384;
            int h = rem >> 6, d = rem & 63;
            int gr0 = row0 + wm * 64 + mi * 16 + ((lane >> 4) << 2);
#pragma unroll
            for (int j = 0; j < 4; ++j) {
                int gr = gr0 + j;
                int b = gr >> 8, t = gr & 255;
                int bh = b * N_HEAD + h;
                __hip_bfloat16 v = __float2bfloat16(acc[mi][ni][j]);
                if (which == 0)      qb[(((size_t)bh << 8) + t) * 64 + d] = v;
                else if (which == 1) kb[(((size_t)bh << 8) + t) * 64 + d] = v;
                else                 vt[(((size_t)bh << 6) + d) * SEQ + t] = v;
            }
        }
    }
}

// ---------------- fused GEMM + residual + LayerNorm (issue-early dbuf) ----------
// tile 32 rows x 384 cols, 4 waves, grid 128 blocks.
template <int RELU>
__global__ __launch_bounds__(256) void egemm_ln(const __hip_bfloat16* __restrict__ A,
                                                const __hip_bfloat16* __restrict__ Bt,
                                                const float* __restrict__ bias,
                                                const float* __restrict__ xin,
                                                float* __restrict__ xout,
                                                const float* __restrict__ g,
                                                const float* __restrict__ bvec,
                                                __hip_bfloat16* __restrict__ hout) {
    __shared__ __align__(1024) char lds[106496];  // [buf][B 48K | A 4K]; xt aliases after loop
    float* xt = (float*)lds;                      // [32][392] f32
    int tid = threadIdx.x;
    int lane = tid & 63, w = tid >> 6;
    int row0 = blockIdx.x * 32;

    f32x4 acc[2][6];
#pragma unroll
    for (int i = 0; i < 2; ++i)
#pragma unroll
        for (int j = 0; j < 6; ++j) acc[i][j] = (f32x4){0.f, 0.f, 0.f, 0.f};

    auto stage = [&](int buf, int k0) {
        char* Bb = lds + buf * 53248;
        char* Ab = Bb + 49152;
        {   // A: 32 rows x 128B
            int p  = tid * 16;
            int lg = p ^ (((p >> 7) & 7) << 4);
            int r  = lg >> 7, cb = lg & 127;
            gload16((const char*)(A + (size_t)(row0 + r) * E_DIM + k0) + cb, Ab + w * 1024);
        }
#pragma unroll
        for (int i = 0; i < 12; ++i) {   // B: 384 rows x 128B
            int p  = i * 4096 + tid * 16;
            int lg = p ^ (((p >> 7) & 7) << 4);
            int r  = lg >> 7, cb = lg & 127;
            gload16((const char*)(Bt + (size_t)r * E_DIM + k0) + cb, Bb + i * 4096 + w * 1024);
        }
    };

    stage(0, 0);
    for (int kt = 0; kt < 6; ++kt) {
        __syncthreads();
        if (kt < 5) stage((kt + 1) & 1, (kt + 1) * 64);
        const char* Bb = lds + (kt & 1) * 53248;
        const char* Ab = Bb + 49152;
#pragma unroll
        for (int ks = 0; ks < 2; ++ks) {
            bf16x8 af[2], bfr[6];
#pragma unroll
            for (int mi = 0; mi < 2; ++mi) {
                int rl = mi * 16 + (lane & 15);
                int lg = rl * 128 + ks * 64 + ((lane >> 4) << 4);
                int ph = lg ^ ((rl & 7) << 4);
                af[mi] = *(const bf16x8*)(Ab + ph);
            }
#pragma unroll
            for (int ni = 0; ni < 6; ++ni) {
                int rl = w * 96 + ni * 16 + (lane & 15);
                int lg = rl * 128 + ks * 64 + ((lane >> 4) << 4);
                int ph = lg ^ ((rl & 7) << 4);
                bfr[ni] = *(const bf16x8*)(Bb + ph);
            }
#pragma unroll
            for (int mi = 0; mi < 2; ++mi)
#pragma unroll
                for (int ni = 0; ni < 6; ++ni)
                    acc[mi][ni] = __builtin_amdgcn_mfma_f32_16x16x32_bf16(
                        af[mi], bfr[ni], acc[mi][ni], 0, 0, 0);
        }
    }
    __syncthreads();   // all frag reads + stage writes done before xt overwrite

    // residual + bias (+relu), write xout and LDS tile
#pragma unroll
    for (int mi = 0; mi < 2; ++mi) {
#pragma unroll
        for (int ni = 0; ni < 6; ++ni) {
            int gc = w * 96 + ni * 16 + (lane & 15);
            int lr0 = mi * 16 + ((lane >> 4) << 2);
            float bv = bias[gc];
#pragma unroll
            for (int j = 0; j < 4; ++j) {
                int lr = lr0 + j;
                float u = acc[mi][ni][j] + bv;
                if (RELU) u = fmaxf(u, 0.f);
                float xn = xin[(size_t)(row0 + lr) * E_DIM + gc] + u;
                xout[(size_t)(row0 + lr) * E_DIM + gc] = xn;
                xt[lr * 392 + gc] = xn;
            }
        }
    }
    __syncthreads();

    // LayerNorm: 8 rows per wave
#pragma unroll
    for (int r8 = 0; r8 < 8; ++r8) {
        int r = w * 8 + r8;
        float v[6];
        float s = 0.f;
#pragma unroll
        for (int c = 0; c < 6; ++c) { v[c] = xt[r * 392 + lane + 64 * c]; s += v[c]; }
#pragma unroll
        for (int off = 32; off > 0; off >>= 1) s += __shfl_xor(s, off);
        float mu = s * (1.0f / E_DIM);
        float s2 = 0.f;
#pragma unroll
        for (int c = 0; c < 6; ++c) { float d = v[c] - mu; s2 += d * d; }
#pragma unroll
        for (int off = 32; off > 0; off >>= 1) s2 += __shfl_xor(s2, off);
        float rstd = rsqrtf(s2 * (1.0f / E_DIM) + 1e-5f);
        __hip_bfloat16* hr = hout + (size_t)(row0 + r) * E_DIM;
#pragma unroll
        for (int c = 0; c < 6; ++c) {
            int e = lane + 64 * c;
            hr[e] = __float2bfloat16((v[c] - mu) * rstd * g[e] + bvec[e]);
        }
    }
}

// ---------------- LM-head GEMM (128x128, XOR-swizzled LDS, XCD swizzle) --------
__global__ __launch_bounds__(256) void mgemm_lm(const __hip_bfloat16* __restrict__ A,
                                                const __hip_bfloat16* __restrict__ Bt,
                                                const float* __restrict__ bias,
                                                float* __restrict__ C) {
    __shared__ __align__(1024) char lds[32768];
    char* Ar = lds;
    char* Br = lds + 16384;
    int tid = threadIdx.x;
    int lane = tid & 63, w = tid >> 6;
    int wm = w >> 1, wn = w & 1;

    // bijective XCD swizzle: grid 393x32 = 12576 = 8*1572 (T1; nwg%8==0)
    int wg  = blockIdx.y * 393 + blockIdx.x;
    int swz = (wg & 7) * 1572 + (wg >> 3);
    int bx  = swz % 393, by = swz / 393;
    int row0 = by * 128;
    int col0 = bx * 128;

    f32x4 acc[4][4];
#pragma unroll
    for (int i = 0; i < 4; ++i)
#pragma unroll
        for (int j = 0; j < 4; ++j) acc[i][j] = (f32x4){0.f, 0.f, 0.f, 0.f};

    for (int k0 = 0; k0 < E_DIM; k0 += 64) {
        __syncthreads();
#pragma unroll
        for (int i = 0; i < 4; ++i) {
            int p  = i * 4096 + tid * 16;
            int lg = p ^ (((p >> 7) & 7) << 4);
            int r  = lg >> 7, cb = lg & 127;
            gload16((const char*)(A  + (size_t)(row0 + r) * E_DIM + k0) + cb, Ar + i * 4096 + w * 1024);
            gload16((const char*)(Bt + (size_t)(col0 + r) * E_DIM + k0) + cb, Br + i * 4096 + w * 1024);
        }
        __syncthreads();
#pragma unroll
        for (int ks = 0; ks < 2; ++ks) {
            bf16x8 af[4], bfr[4];
#pragma unroll
            for (int mi = 0; mi < 4; ++mi) {
                int rl = wm * 64 + mi * 16 + (lane & 15);
                int lg = rl * 128 + ks * 64 + ((lane >> 4) << 4);
                int ph = lg ^ ((rl & 7) << 4);
                af[mi] = *(const bf16x8*)(Ar + ph);
            }
#pragma unroll
            for (int ni = 0; ni < 4; ++ni) {
                int rl = wn * 64 + ni * 16 + (lane & 15);
                int lg = rl * 128 + ks * 64 + ((lane >> 4) << 4);
                int ph = lg ^ ((rl & 7) << 4);
                bfr[ni] = *(const bf16x8*)(Br + ph);
            }
#pragma unroll
            for (int mi = 0; mi < 4; ++mi)
#pragma unroll
                for (int ni = 0; ni < 4; ++ni)
                    acc[mi][ni] = __builtin_amdgcn_mfma_f32_16x16x32_bf16(
                        af[mi], bfr[ni], acc[mi][ni], 0, 0, 0);
        }
    }

#pragma unroll
    for (int mi = 0; mi < 4; ++mi) {
#pragma unroll
        for (int ni = 0; ni < 4; ++ni) {
            int gr = row0 + wm * 64 + mi * 16 + ((lane >> 4) << 2);
            int gc = col0 + wn * 64 + ni * 16 + (lane & 15);
            if (gc < VOCAB) {
                float bv = bias[gc];
#pragma unroll
                for (int j = 0; j < 4; ++j)
                    C[(size_t)(gr + j) * VOCAB + gc] = acc[mi][ni][j] + bv;
            }
        }
    }
}

// ---------------- fused MFMA attention (72 KB LDS, P aliases K) -------
#define ATT_K 0
#define ATT_V 32768
#define ATT_Q 65536

__global__ __launch_bounds__(256) void attn_fused(const __hip_bfloat16* __restrict__ qb,
                                                  const __hip_bfloat16* __restrict__ kb,
                                                  const __hip_bfloat16* __restrict__ vt,
                                                  __hip_bfloat16* __restrict__ o) {
    __shared__ __align__(1024) char lds[73728];
    int tid = threadIdx.x;
    int lane = tid & 63, w = tid >> 6;
    int bh = blockIdx.x;
    int mq = blockIdx.y;
    int b = bh / N_HEAD, h = bh - b * N_HEAD;

    const char* kg = (const char*)(kb + (size_t)bh * SEQ * 64);
#pragma unroll
    for (int i = 0; i < 8; ++i) {
        int p = i * 4096 + tid * 16;
        int lg = p ^ (((p >> 7) & 7) << 4);
        gload16(kg + lg, lds + ATT_K + p);
    }
    const char* vg = (const char*)(vt + (size_t)bh * 64 * SEQ);
#pragma unroll
    for (int i = 0; i < 8; ++i) {
        int p = i * 4096 + tid * 16;
        int lg = p ^ (((p >> 9) & 7) << 4);
        gload16(vg + lg, lds + ATT_V + p);
    }
    const char* qg = (const char*)(qb + ((size_t)bh * SEQ + mq * 64) * 64);
#pragma unroll
    for (int i = 0; i < 2; ++i) {
        int p = i * 4096 + tid * 16;
        int lg = p ^ (((p >> 7) & 7) << 4);
        gload16(qg + lg, lds + ATT_Q + p);
    }
    __syncthreads();

    int q0 = w * 16;
    int qg0 = mq * 64 + q0;

    f32x4 acc[16];
#pragma unroll
    for (int n = 0; n < 16; ++n) acc[n] = (f32x4){0.f, 0.f, 0.f, 0.f};
#pragma unroll
    for (int ks = 0; ks < 2; ++ks) {
        int rq = q0 + (lane & 15);
        int byq = (ks * 64 + ((lane >> 4) << 4)) ^ ((rq & 7) << 4);
        bf16x8 aq = *(const bf16x8*)(lds + ATT_Q + rq * 128 + byq);
#pragma unroll
        for (int n = 0; n < 16; ++n) {
            int rk = n * 16 + (lane & 15);
            int byk = (ks * 64 + ((lane >> 4) << 4)) ^ ((rk & 7) << 4);
            bf16x8 bk = *(const bf16x8*)(lds + ATT_K + rk * 128 + byk);
            acc[n] = __builtin_amdgcn_mfma_f32_16x16x32_bf16(aq, bk, acc[n], 0, 0, 0);
        }
    }
    __syncthreads();   // all K reads done; P may overwrite K region

    char* pbase = lds + ATT_K + w * 8192;   // per-wave [16][256] bf16
#pragma unroll
    for (int j = 0; j < 4; ++j) {
        int rql = ((lane >> 4) << 2) + j;
        int rg = qg0 + rql;
        float s[16];
        float m = -INFINITY;
#pragma unroll
        for (int n = 0; n < 16; ++n) {
            int cg = n * 16 + (lane & 15);
            float v = (cg <= rg) ? acc[n][j] * 0.125f : -INFINITY;
            s[n] = v;
            m = fmaxf(m, v);
        }
#pragma unroll
        for (int off = 1; off < 16; off <<= 1) m = fmaxf(m, __shfl_xor(m, off));
        float sum = 0.f;
#pragma unroll
        for (int n = 0; n < 16; ++n) { s[n] = __expf(s[n] - m); sum += s[n]; }
#pragma unroll
        for (int off = 1; off < 16; off <<= 1) sum += __shfl_xor(sum, off);
        float inv = 1.0f / sum;
#pragma unroll
        for (int n = 0; n < 16; ++n) {
            int cg = n * 16 + (lane & 15);
            int by = (cg * 2) ^ ((rql & 7) << 4);
            *(__hip_bfloat16*)(pbase + rql * 512 + by) = __float2bfloat16(s[n] * inv);
        }
    }

    f32x4 oacc[4];
#pragma unroll
    for (int nf = 0; nf < 4; ++nf) oacc[nf] = (f32x4){0.f, 0.f, 0.f, 0.f};
#pragma unroll
    for (int ks = 0; ks < 8; ++ks) {
        int rp = lane & 15;
        int byp = (ks * 64 + ((lane >> 4) << 4)) ^ ((rp & 7) << 4);
        bf16x8 ap = *(const bf16x8*)(pbase + rp * 512 + byp);
#pragma unroll
        for (int nf = 0; nf < 4; ++nf) {
            int rv = nf * 16 + (lane & 15);
            int byv = (ks * 64 + ((lane >> 4) << 4)) ^ ((rv & 7) << 4);
            bf16x8 bv = *(const bf16x8*)(lds + ATT_V + rv * 512 + byv);
            oacc[nf] = __builtin_amdgcn_mfma_f32_16x16x32_bf16(ap, bv, oacc[nf], 0, 0, 0);
        }
    }

#pragma unroll
    for (int nf = 0; nf < 4; ++nf) {
#pragma unroll
        for (int j = 0; j < 4; ++j) {
            int t = mq * 64 + q0 + ((lane >> 4) << 2) + j;
            int d = nf * 16 + (lane & 15);
            o[(size_t)(b * SEQ + t) * E_DIM + h * 64 + d] = __float2bfloat16(oacc[nf][j]);
        }
    }
}

extern "C" void kernel_launch(void* const* d_in, const int* in_sizes, int n_in,
                              void* d_out, int out_size, void* d_ws, size_t ws_size,
                              hipStream_t stream) {
    const int*   idx  = (const int*)d_in[0];
    const float* tok  = (const float*)d_in[1];
    const float* pos  = (const float*)d_in[2];
    const float* Wq   = (const float*)d_in[3];
    const float* Wk   = (const float*)d_in[4];
    const float* Wv   = (const float*)d_in[5];
    const float* Wo   = (const float*)d_in[6];
    const float* bo   = (const float*)d_in[7];
    const float* ln1g = (const float*)d_in[8];
    const float* ln1b = (const float*)d_in[9];
    const float* ln2g = (const float*)d_in[10];
    const float* ln2b = (const float*)d_in[11];
    const float* Wm   = (const float*)d_in[12];
    const float* bm   = (const float*)d_in[13];
    const float* lnfg = (const float*)d_in[14];
    const float* lnfb = (const float*)d_in[15];
    const float* Wlm  = (const float*)d_in[16];
    const float* blm  = (const float*)d_in[17];
    float* out = (float*)d_out;

    float*           x    = (float*)d_ws;                         // [4096][384] f32
    __hip_bfloat16*  hb   = (__hip_bfloat16*)(x + (size_t)NTOK * E_DIM);
    __hip_bfloat16*  WtL  = hb + (size_t)NTOK * E_DIM;
    __hip_bfloat16*  WtLM = WtL + (size_t)NLAYER * 1920 * E_DIM;  // [50304][384]
    __hip_bfloat16*  qbv  = WtLM + (size_t)VPAD * E_DIM;
    __hip_bfloat16*  kbv  = qbv + (size_t)NBH * SEQ * 64;
    __hip_bfloat16*  vtb  = kbv + (size_t)NBH * SEQ * 64;

    embed_kernel<<<(NTOK * E_DIM + 255) / 256, 256, 0, stream>>>(idx, tok, pos, x);
    tconv_layers<<<dim3(6, 6, NLAYER * 5), 256, 0, stream>>>(Wq, Wk, Wv, Wo, Wm, WtL);
    tconv_lm<<<dim3(VPAD / 64, E_DIM / 64), 256, 0, stream>>>(Wlm, WtLM);
    ln_kernel<<<NTOK / 4, 256, 0, stream>>>(x, ln1g, ln1b, hb);

    for (int l = 0; l < NLAYER; ++l) {
        const __hip_bfloat16* wl = WtL + (size_t)l * 1920 * E_DIM;
        qkvgemm<<<dim3(QKV_N / 128, NTOK / 128), 256, 0, stream>>>(hb, wl, qbv, kbv, vtb);
        attn_fused<<<dim3(NBH, 4), 256, 0, stream>>>(qbv, kbv, vtb, hb);
        egemm_ln<0><<<NTOK / 32, 256, 0, stream>>>(hb, wl + (size_t)1152 * E_DIM,
                                                   bo + l * E_DIM, x, x,
                                                   ln2g + l * E_DIM, ln2b + l * E_DIM, hb);
        const float* ng = (l == NLAYER - 1) ? lnfg : ln1g + (l + 1) * E_DIM;
        const float* nb = (l == NLAYER - 1) ? lnfb : ln1b + (l + 1) * E_DIM;
        egemm_ln<1><<<NTOK / 32, 256, 0, stream>>>(hb, wl + (size_t)1536 * E_DIM,
                                                   bm + l * E_DIM, x, x,
                                                   ng, nb, hb);
    }

    mgemm_lm<<<dim3(VPAD / 128, NTOK / 128), 256, 0, stream>>>(hb, WtLM, blm, out);
}